// Round 2
// baseline (558.663 us; speedup 1.0000x reference)
//
#include <hip/hip_runtime.h>
#include <hip/hip_bf16.h>
#include <stdint.h>

// Problem constants
#define A_N 8
#define B_N 32768
#define IN_N 128
#define OUT_N 32
#define SAF 160      // IN + OUT  (= enc K, exactly 5 x 32: NO pad)
#define H_N 128
#define D_N 32
#define KD_N 128     // K*D
#define CIN_N 256    // critic input = H + K*D
#define CHUNKS 128   // stats chunks over B
#define EPSV 1e-5f

typedef unsigned int u32;
typedef unsigned short u16;
typedef __attribute__((ext_vector_type(8))) short short8;    // 8 bf16 (4 VGPRs)
typedef __attribute__((ext_vector_type(4))) float floatx4;   // MFMA C/D

// async global->LDS, 16B per lane. LDS dest = wave-uniform base + lane*16,
// so dest layout MUST be linear in lane order.
typedef __attribute__((address_space(1))) void gvoid;
typedef __attribute__((address_space(3))) void lvoid;
__device__ __forceinline__ void glds16(const void* g, void* l){
  __builtin_amdgcn_global_load_lds((gvoid*)g, (lvoid*)l, 16, 0, 0);
}

// 16B-unit XOR swizzle (involution). Tiles are [rows][32 k] u16 = [rows][4
// units]; swz spreads frag-read rows over all 8 bank-quads. Because glds
// can't scatter its LDS dest, the swizzle is applied on the GLOBAL SOURCE
// address (permutes within 64B -> coalescing preserved) and again on the
// frag-read address (XOR is self-inverse).
__device__ __forceinline__ int swzu(int u){ return u ^ ((u >> 3) & 3); }

__device__ __forceinline__ void hard_barrier(){
  asm volatile("" ::: "memory");
  __builtin_amdgcn_s_barrier();
  asm volatile("" ::: "memory");
}

__device__ __forceinline__ float bf_lo(u32 u){ return __uint_as_float(u << 16); }
__device__ __forceinline__ float bf_hi(u32 u){ return __uint_as_float(u & 0xffff0000u); }
__device__ __forceinline__ float bf2f(u16 b){ return __uint_as_float(((u32)b) << 16); }
__device__ __forceinline__ u16 f2bf(float f){
  u32 u = __float_as_uint(f);
  return (u16)((u + 0x7fffu + ((u >> 16) & 1u)) >> 16);
}
__device__ __forceinline__ float lrelu(float x){ return x > 0.f ? x : 0.01f * x; }

// ---------------------------------------------------------------------------
// Stage 1: BN statistics (sum, sumsq) per (agent, feature).
// ---------------------------------------------------------------------------
__global__ __launch_bounds__(256) void k_stats(
    const float* __restrict__ states, const float* __restrict__ actions,
    float* __restrict__ part)
{
  int a = blockIdx.y;
  int chunk = blockIdx.x;
  int t = threadIdx.x;
  int r0 = chunk * (B_N / CHUNKS);   // 256 rows per chunk
  __shared__ float red[512];
  {
    int f = t & 127, half = t >> 7;
    const float* p = states + ((size_t)a * B_N + r0 + half) * IN_N + f;
    float s1 = 0.f, s2 = 0.f;
    for (int it = 0; it < 128; ++it){
      float v = p[(size_t)(2 * it) * IN_N];
      s1 += v; s2 += v * v;
    }
    red[t] = s1; red[256 + t] = s2;
    __syncthreads();
    if (t < 128){
      float a1 = red[t] + red[t + 128];
      float a2 = red[256 + t] + red[256 + t + 128];
      size_t o = (((size_t)a * CHUNKS + chunk) * SAF + t) * 2;
      part[o] = a1; part[o + 1] = a2;
    }
    __syncthreads();
  }
  {
    int f = t & 31, g = t >> 5;
    const float* p = actions + ((size_t)a * B_N + r0 + g) * OUT_N + f;
    float s1 = 0.f, s2 = 0.f;
    for (int it = 0; it < 32; ++it){
      float v = p[(size_t)(8 * it) * OUT_N];
      s1 += v; s2 += v * v;
    }
    red[t] = s1; red[256 + t] = s2;
    __syncthreads();
    if (t < 32){
      float a1 = 0.f, a2 = 0.f;
      #pragma unroll
      for (int gg = 0; gg < 8; ++gg){
        a1 += red[t + 32 * gg];
        a2 += red[256 + t + 32 * gg];
      }
      size_t o = (((size_t)a * CHUNKS + chunk) * SAF + 128 + t) * 2;
      part[o] = a1; part[o + 1] = a2;
    }
  }
}

__global__ void k_finalize(const float* __restrict__ part,
                           float* __restrict__ meanArr, float* __restrict__ istdArr)
{
  int idx = blockIdx.x * blockDim.x + threadIdx.x;
  if (idx >= A_N * SAF) return;
  int a = idx / SAF, f = idx % SAF;
  float s1 = 0.f, s2 = 0.f;
  for (int c = 0; c < CHUNKS; ++c){
    size_t o = (((size_t)a * CHUNKS + c) * SAF + f) * 2;
    s1 += part[o]; s2 += part[o + 1];
  }
  float m = s1 * (1.f / B_N);
  float v = s2 * (1.f / B_N) - m * m;
  if (v < 0.f) v = 0.f;
  meanArr[idx] = m;
  istdArr[idx] = rsqrtf(v + EPSV);
}

// ---------------------------------------------------------------------------
// Weight pre-pack, TILE-MAJOR for global_load_lds:
//   layout = [k-tile][128 n][32 k] contiguous (4096 u16 = 8192 B per tile).
// enc/c1: hi/lo bf16 pairs; key/sel/val: single bf16.
// ---------------------------------------------------------------------------
__device__ __forceinline__ void packpair(float w, u16* __restrict__ dh,
                                         u16* __restrict__ dl, int i){
  u16 h = f2bf(w);
  dh[i] = h;
  dl[i] = f2bf(w - bf2f(h));
}

__global__ __launch_bounds__(256) void k_pack(
    const float* __restrict__ enc_w, const float* __restrict__ aenc_w,
    const float* __restrict__ key_w, const float* __restrict__ sel_w,
    const float* __restrict__ val_w, const float* __restrict__ c1_w,
    u16* __restrict__ encH, u16* __restrict__ encL,
    u16* __restrict__ aencH, u16* __restrict__ aencL,
    u16* __restrict__ keyH, u16* __restrict__ selH, u16* __restrict__ valH,
    u16* __restrict__ c1H, u16* __restrict__ c1L)
{
  int i = blockIdx.x * 256 + threadIdx.x;
  const int S0 = A_N * H_N * SAF;      // 163840 enc (5 tiles/agent)
  const int S1 = A_N * H_N * OUT_N;    // 32768 aenc
  const int S2 = KD_N * H_N;           // 16384 per key/sel/val (4 tiles)
  const int S5 = A_N * H_N * CIN_N;    // 262144 c1 (8 tiles/agent)
  if (i < S0){
    int a = i / (H_N * SAF); int r = i % (H_N * SAF);
    int tile = r >> 12; int rr = r & 4095;
    int n = rr >> 5; int kk = rr & 31;
    int kg = tile * 32 + kk;
    packpair(enc_w[((size_t)a * SAF + kg) * H_N + n], encH, encL, i);
    return;
  }
  i -= S0;
  if (i < S1){
    int a = i >> 12; int rr = i & 4095;
    int n = rr >> 5; int k = rr & 31;
    packpair(aenc_w[((size_t)a * OUT_N + k) * H_N + n], aencH, aencL, i);
    return;
  }
  i -= S1;
  if (i < 3 * S2){
    int which = i / S2; int j = i % S2;
    int tile = j >> 12; int rr = j & 4095;
    int n = rr >> 5; int kk = rr & 31;
    int kg = tile * 32 + kk;
    const float* w = (which == 0) ? key_w : ((which == 1) ? sel_w : val_w);
    u16* dh = (which == 0) ? keyH : ((which == 1) ? selH : valH);
    dh[j] = f2bf(w[(((size_t)(n >> 5)) * H_N + kg) * D_N + (n & 31)]);
    return;
  }
  i -= 3 * S2;
  if (i < S5){
    int a = i >> 15; int r = i & 32767;
    int tile = r >> 12; int rr = r & 4095;
    int n = rr >> 5; int kk = rr & 31;
    int kg = tile * 32 + kk;
    packpair(c1_w[((size_t)a * CIN_N + kg) * H_N + n], c1H, c1L, i);
  }
}
#define PACK_TOTAL (A_N*H_N*SAF + A_N*H_N*OUT_N + 3*KD_N*H_N + A_N*H_N*CIN_N)

// ---------------------------------------------------------------------------
// Fused kernel 1: sa_enc = lrelu(BN(concat) @ enc_w + enc_b)  [3-term, BK=32,
//   K=160], sels = sa_enc @ sel_w [1-term].
// Pipelined: X reg-prefetch (T14) + post-barrier W glds + counted vmcnt +
// raw barriers (no full drains in the K-loop). W tiles swizzle-staged.
// ---------------------------------------------------------------------------
__global__ __launch_bounds__(256, 3) void k_enc_sel(
    const float* __restrict__ states, const float* __restrict__ actions,
    const float* __restrict__ mean, const float* __restrict__ istd,
    const u16* __restrict__ encH, const u16* __restrict__ encL,
    const float* __restrict__ enc_b,
    const u16* __restrict__ selH,
    u16* __restrict__ sa_enc, u16* __restrict__ sels)
{
  int a = blockIdx.y; int row0 = blockIdx.x * 128; int t = threadIdx.x;
  int lane = t & 63, wave = t >> 6, l16 = lane & 15, quad = lane >> 4;
  __shared__ __align__(16) u16 S[25600];
  __shared__ __align__(16) float sc[160], sh[160];
  u16* Wh = S;            // [128][32] enc weight hi tile (phase 1)
  u16* Wl = S + 4096;     // [128][32]
  u16* Xh = S + 8192;     // [128][40]
  u16* Xl = S + 13312;    // [128][40]
  u16* T  = S;            // [128][136] (phase-1 output / phase-2 A)
  u16* Ws = S + 17408;    // [2][128][32] sel weight tiles (phase 2)

  if (t < SAF){
    float m = mean[a * SAF + t], s = istd[a * SAF + t];
    sc[t] = s; sh[t] = -m * s;
  }
  floatx4 acc[2][8];
  #pragma unroll
  for (int mt = 0; mt < 2; ++mt)
    #pragma unroll
    for (int nt = 0; nt < 8; ++nt) acc[mt][nt] = (floatx4){0.f,0.f,0.f,0.f};
  const u16* ebh = encH + (size_t)a * (H_N * SAF);
  const u16* ebl = encL + (size_t)a * (H_N * SAF);
  __syncthreads();

  // ---- phase 1 prologue: X(0) regs + W(0) glds ----
  float4 xr[4];
  #pragma unroll
  for (int ci = 0; ci < 4; ++ci){
    int c = t + ci * 256;
    int r = c >> 3, kc = (c & 7) * 4;
    xr[ci] = *(const float4*)(states + ((size_t)a * B_N + row0 + r) * IN_N + kc);
  }
  #pragma unroll
  for (int c = t; c < 512; c += 256){
    glds16(ebh + swzu(c) * 8, Wh + c * 8);
    glds16(ebl + swzu(c) * 8, Wl + c * 8);
  }
  asm volatile("" ::: "memory");

  // ---- phase 1 K-loop: 5 tiles, counted vmcnt ----
  #pragma unroll
  for (int kt = 0; kt < 5; ++kt){
    int k0 = kt * 32;
    // transform current X regs -> hi/lo bf16 -> LDS (stride 40)
    #pragma unroll
    for (int ci = 0; ci < 4; ++ci){
      int c = t + ci * 256;
      int r = c >> 3, kc = (c & 7) * 4, f = k0 + kc;
      float4 v = xr[ci];
      float4 scv = *(const float4*)&sc[f];
      float4 shv = *(const float4*)&sh[f];
      float x0 = fmaf(v.x, scv.x, shv.x), x1 = fmaf(v.y, scv.y, shv.y);
      float x2 = fmaf(v.z, scv.z, shv.z), x3 = fmaf(v.w, scv.w, shv.w);
      u16 h0 = f2bf(x0), h1 = f2bf(x1), h2 = f2bf(x2), h3 = f2bf(x3);
      uint2 hv; hv.x = (u32)h0 | ((u32)h1 << 16); hv.y = (u32)h2 | ((u32)h3 << 16);
      *(uint2*)&Xh[r * 40 + kc] = hv;
      u16 l0 = f2bf(x0 - bf2f(h0)), l1 = f2bf(x1 - bf2f(h1));
      u16 l2 = f2bf(x2 - bf2f(h2)), l3 = f2bf(x3 - bf2f(h3));
      uint2 lv; lv.x = (u32)l0 | ((u32)l1 << 16); lv.y = (u32)l2 | ((u32)l3 << 16);
      *(uint2*)&Xl[r * 40 + kc] = lv;
    }
    // prefetch next X tile into regs (stays in flight across both barriers)
    if (kt < 4){
      #pragma unroll
      for (int ci = 0; ci < 4; ++ci){
        int c = t + ci * 256;
        int r = c >> 3, kc = (c & 7) * 4;
        size_t row = (size_t)a * B_N + row0 + r;
        if (kt < 3) xr[ci] = *(const float4*)(states + row * IN_N + (kt + 1) * 32 + kc);
        else        xr[ci] = *(const float4*)(actions + row * OUT_N + kc);
      }
      asm volatile("s_waitcnt vmcnt(4) lgkmcnt(0)" ::: "memory"); // W(kt) done
    } else {
      asm volatile("s_waitcnt vmcnt(0) lgkmcnt(0)" ::: "memory");
    }
    __builtin_amdgcn_s_barrier();
    asm volatile("" ::: "memory");
    {
      short8 ah[2], al[2], bh[8], bl[8];
      #pragma unroll
      for (int mt = 0; mt < 2; ++mt){
        int rr = (wave * 32 + mt * 16 + l16) * 40 + quad * 8;
        ah[mt] = *(const short8*)&Xh[rr];
        al[mt] = *(const short8*)&Xl[rr];
      }
      #pragma unroll
      for (int nt = 0; nt < 8; ++nt){
        int v = (nt * 16 + l16) * 4 + quad; v ^= (v >> 3) & 3;
        bh[nt] = *(const short8*)&Wh[v * 8];
        bl[nt] = *(const short8*)&Wl[v * 8];
      }
      #pragma unroll
      for (int mt = 0; mt < 2; ++mt)
        #pragma unroll
        for (int nt = 0; nt < 8; ++nt){
          acc[mt][nt] = __builtin_amdgcn_mfma_f32_16x16x32_bf16(ah[mt], bh[nt], acc[mt][nt], 0,0,0);
          acc[mt][nt] = __builtin_amdgcn_mfma_f32_16x16x32_bf16(ah[mt], bl[nt], acc[mt][nt], 0,0,0);
          acc[mt][nt] = __builtin_amdgcn_mfma_f32_16x16x32_bf16(al[mt], bh[nt], acc[mt][nt], 0,0,0);
        }
    }
    hard_barrier();
    if (kt < 4){
      const u16* th = ebh + (kt + 1) * 4096;
      const u16* tl = ebl + (kt + 1) * 4096;
      #pragma unroll
      for (int c = t; c < 512; c += 256){
        glds16(th + swzu(c) * 8, Wh + c * 8);
        glds16(tl + swzu(c) * 8, Wl + c * 8);
      }
      asm volatile("" ::: "memory");
    }
  }

  // ---- phase-1 epilogue: lrelu+bias -> bf16 tile T in LDS ----
  {
    float bv[8];
    #pragma unroll
    for (int nt = 0; nt < 8; ++nt) bv[nt] = enc_b[a * H_N + nt * 16 + l16];
    #pragma unroll
    for (int mt = 0; mt < 2; ++mt)
      #pragma unroll
      for (int nt = 0; nt < 8; ++nt)
        #pragma unroll
        for (int r = 0; r < 4; ++r){
          int rl = wave * 32 + mt * 16 + quad * 4 + r;
          T[rl * 136 + nt * 16 + l16] = f2bf(lrelu(acc[mt][nt][r] + bv[nt]));
        }
  }
  __syncthreads();
  // prefetch sel tiles 0,1 -- latency hides under the sa_enc store
  #pragma unroll
  for (int c = t; c < 1024; c += 256)
    glds16(selH + swzu(c) * 8, Ws + c * 8);
  asm volatile("" ::: "memory");
  for (int c = t; c < 2048; c += 256){
    int row = c >> 4, col8 = (c & 15) * 8;
    *(uint4*)(sa_enc + ((size_t)a * B_N + row0 + row) * H_N + col8) =
        *(const uint4*)&T[row * 136 + col8];
  }
  #pragma unroll
  for (int mt = 0; mt < 2; ++mt)
    #pragma unroll
    for (int nt = 0; nt < 8; ++nt) acc[mt][nt] = (floatx4){0.f,0.f,0.f,0.f};

  // ---- phase 2: sels = T @ selT ----
  asm volatile("s_waitcnt vmcnt(0)" ::: "memory");
  __builtin_amdgcn_s_barrier();
  asm volatile("" ::: "memory");
  #pragma unroll
  for (int k0 = 0; k0 < H_N; k0 += 64){
    #pragma unroll
    for (int ks = 0; ks < 64; ks += 32){
      short8 ah[2], bh[8];
      #pragma unroll
      for (int mt = 0; mt < 2; ++mt)
        ah[mt] = *(const short8*)&T[(wave * 32 + mt * 16 + l16) * 136 + k0 + ks + quad * 8];
      #pragma unroll
      for (int nt = 0; nt < 8; ++nt){
        int v = ((ks >> 5) << 9) + (nt * 16 + l16) * 4 + quad; v ^= (v >> 3) & 3;
        bh[nt] = *(const short8*)&Ws[v * 8];
      }
      #pragma unroll
      for (int mt = 0; mt < 2; ++mt)
        #pragma unroll
        for (int nt = 0; nt < 8; ++nt)
          acc[mt][nt] = __builtin_amdgcn_mfma_f32_16x16x32_bf16(ah[mt], bh[nt], acc[mt][nt], 0,0,0);
    }
    hard_barrier();
    if (k0 == 0){
      #pragma unroll
      for (int c = t; c < 1024; c += 256)
        glds16(selH + 8192 + swzu(c) * 8, Ws + c * 8);
      asm volatile("s_waitcnt vmcnt(0)" ::: "memory");
      __builtin_amdgcn_s_barrier();
      asm volatile("" ::: "memory");
    }
  }
  #pragma unroll
  for (int mt = 0; mt < 2; ++mt)
    #pragma unroll
    for (int nt = 0; nt < 8; ++nt)
      #pragma unroll
      for (int r = 0; r < 4; ++r){
        int rl = wave * 32 + mt * 16 + quad * 4 + r;
        T[rl * 136 + nt * 16 + l16] = f2bf(acc[mt][nt][r]);
      }
  __syncthreads();
  for (int c = t; c < 2048; c += 256){
    int row = c >> 4, col8 = (c & 15) * 8;
    *(uint4*)(sels + ((size_t)a * B_N + row0 + row) * H_N + col8) =
        *(const uint4*)&T[row * 136 + col8];
  }
}

// ---------------------------------------------------------------------------
// Fused kernel 2: a_enc = lrelu(BN(actions) @ aenc_w + aenc_b) [3-term, K=32]
//   keys & vals in ONE dual-accumulator loop (weights swizzle-staged).
// ---------------------------------------------------------------------------
__global__ __launch_bounds__(256, 2) void k_aenc_kv(
    const float* __restrict__ actions,
    const float* __restrict__ mean, const float* __restrict__ istd,
    const u16* __restrict__ aencH, const u16* __restrict__ aencL,
    const float* __restrict__ aenc_b,
    const u16* __restrict__ keyH, const u16* __restrict__ valH,
    const float* __restrict__ val_b,
    u16* __restrict__ keys, u16* __restrict__ vals)
{
  int a = blockIdx.y; int row0 = blockIdx.x * 128; int t = threadIdx.x;
  int lane = t & 63, wave = t >> 6, l16 = lane & 15, quad = lane >> 4;
  __shared__ __align__(16) u16 S[34816];
  __shared__ __align__(16) float sc[32], sh[32];
  u16* T  = S;            // [128][136] a_enc tile; later vals tile
  u16* WK = S + 17408;    // [2][128][32] key weight tiles
  u16* WV = S + 25600;    // [2][128][32] val weight tiles
  u16* T2 = S + 17408;    // [128][136] keys tile (epilogue)

  if (t < 32){
    float m = mean[a * SAF + 128 + t], s = istd[a * SAF + 128 + t];
    sc[t] = s; sh[t] = -m * s;
  }
  floatx4 accK[2][8], accV[2][8];
  #pragma unroll
  for (int mt = 0; mt < 2; ++mt)
    #pragma unroll
    for (int nt = 0; nt < 8; ++nt){
      accK[mt][nt] = (floatx4){0.f,0.f,0.f,0.f};
      accV[mt][nt] = (floatx4){0.f,0.f,0.f,0.f};
    }
  __syncthreads();

  // ---- phase 1: aenc GEMM, K=32 single tile ----
  {
    u16* Wh1 = S;  u16* Wl1 = S + 4096;
    u16* Xh = S + 8192; u16* Xl = S + 13312;  // [128][40]
    const u16* abh = aencH + (size_t)a * 4096;
    const u16* abl = aencL + (size_t)a * 4096;
    #pragma unroll
    for (int c = t; c < 512; c += 256){
      glds16(abh + swzu(c) * 8, Wh1 + c * 8);
      glds16(abl + swzu(c) * 8, Wl1 + c * 8);
    }
    for (int c = t; c < 1024; c += 256){
      int r = c >> 3, kc = (c & 7) * 4;
      size_t row = (size_t)a * B_N + row0 + r;
      float4 v = *(const float4*)(actions + row * OUT_N + kc);
      float4 scv = *(const float4*)&sc[kc];
      float4 shv = *(const float4*)&sh[kc];
      float x0 = fmaf(v.x, scv.x, shv.x), x1 = fmaf(v.y, scv.y, shv.y);
      float x2 = fmaf(v.z, scv.z, shv.z), x3 = fmaf(v.w, scv.w, shv.w);
      u16 h0 = f2bf(x0), h1 = f2bf(x1), h2 = f2bf(x2), h3 = f2bf(x3);
      uint2 hv; hv.x = (u32)h0 | ((u32)h1 << 16); hv.y = (u32)h2 | ((u32)h3 << 16);
      *(uint2*)&Xh[r * 40 + kc] = hv;
      u16 l0 = f2bf(x0 - bf2f(h0)), l1 = f2bf(x1 - bf2f(h1));
      u16 l2 = f2bf(x2 - bf2f(h2)), l3 = f2bf(x3 - bf2f(h3));
      uint2 lv; lv.x = (u32)l0 | ((u32)l1 << 16); lv.y = (u32)l2 | ((u32)l3 << 16);
      *(uint2*)&Xl[r * 40 + kc] = lv;
    }
    __syncthreads();
    short8 ah[2], al[2], bh[8], bl[8];
    #pragma unroll
    for (int mt = 0; mt < 2; ++mt){
      int rr = (wave * 32 + mt * 16 + l16) * 40 + quad * 8;
      ah[mt] = *(const short8*)&Xh[rr];
      al[mt] = *(const short8*)&Xl[rr];
    }
    #pragma unroll
    for (int nt = 0; nt < 8; ++nt){
      int v = (nt * 16 + l16) * 4 + quad; v ^= (v >> 3) & 3;
      bh[nt] = *(const short8*)&Wh1[v * 8];
      bl[nt] = *(const short8*)&Wl1[v * 8];
    }
    #pragma unroll
    for (int mt = 0; mt < 2; ++mt)
      #pragma unroll
      for (int nt = 0; nt < 8; ++nt){
        accK[mt][nt] = __builtin_amdgcn_mfma_f32_16x16x32_bf16(ah[mt], bh[nt], accK[mt][nt], 0,0,0);
        accK[mt][nt] = __builtin_amdgcn_mfma_f32_16x16x32_bf16(ah[mt], bl[nt], accK[mt][nt], 0,0,0);
        accK[mt][nt] = __builtin_amdgcn_mfma_f32_16x16x32_bf16(al[mt], bh[nt], accK[mt][nt], 0,0,0);
      }
    __syncthreads();
  }
  // a_enc -> LDS tile T; move from accK, then zero accK
  {
    float bv[8];
    #pragma unroll
    for (int nt = 0; nt < 8; ++nt) bv[nt] = aenc_b[a * H_N + nt * 16 + l16];
    #pragma unroll
    for (int mt = 0; mt < 2; ++mt)
      #pragma unroll
      for (int nt = 0; nt < 8; ++nt){
        #pragma unroll
        for (int r = 0; r < 4; ++r){
          int rl = wave * 32 + mt * 16 + quad * 4 + r;
          T[rl * 136 + nt * 16 + l16] = f2bf(lrelu(accK[mt][nt][r] + bv[nt]));
        }
        accK[mt][nt] = (floatx4){0.f,0.f,0.f,0.f};
      }
  }

  // ---- phase 2: keys + vals in one dual-acc loop (BK=64, single-term) ----
  for (int k0 = 0; k0 < H_N; k0 += 64){
    __syncthreads();
    #pragma unroll
    for (int c = t; c < 1024; c += 256){
      glds16(keyH + (k0 >> 5) * 4096 + swzu(c) * 8, WK + c * 8);
      glds16(valH + (k0 >> 5) * 4096 + swzu(c) * 8, WV + c * 8);
    }
    __syncthreads();
    #pragma unroll
    for (int ks = 0; ks < 64; ks += 32){
      short8 ah[2], bk[8], bv[8];
      #pragma unroll
      for (int mt = 0; mt < 2; ++mt)
        ah[mt] = *(const short8*)&T[(wave * 32 + mt * 16 + l16) * 136 + k0 + ks + quad * 8];
      #pragma unroll
      for (int nt = 0; nt < 8; ++nt){
        int v = ((ks >> 5) << 9) + (nt * 16 + l16) * 4 + quad; v ^= (v >> 3) & 3;
        bk[nt] = *(const short8*)&WK[v * 8];
        bv[nt] = *(const short8*)&WV[v * 8];
      }
      #pragma unroll
      for (int mt = 0; mt < 2; ++mt)
        #pragma unroll
        for (int nt = 0; nt < 8; ++nt){
          accK[mt][nt] = __builtin_amdgcn_mfma_f32_16x16x32_bf16(ah[mt], bk[nt], accK[mt][nt], 0,0,0);
          accV[mt][nt] = __builtin_amdgcn_mfma_f32_16x16x32_bf16(ah[mt], bv[nt], accV[mt][nt], 0,0,0);
        }
    }
  }
  __syncthreads();
  // epilogue: vals -> T (with bias+lrelu), keys -> T2; both vectorized
  {
    float bv[8];
    #pragma unroll
    for (int nt = 0; nt < 8; ++nt) bv[nt] = val_b[nt * 16 + l16];
    #pragma unroll
    for (int mt = 0; mt < 2; ++mt)
      #pragma unroll
      for (int nt = 0; nt < 8; ++nt)
        #pragma unroll
        for (int r = 0; r < 4; ++r){
          int rl = wave * 32 + mt * 16 + quad * 4 + r;
          T[rl * 136 + nt * 16 + l16]  = f2bf(lrelu(accV[mt][nt][r] + bv[nt]));
          T2[rl * 136 + nt * 16 + l16] = f2bf(accK[mt][nt][r]);
        }
  }
  __syncthreads();
  for (int c = t; c < 2048; c += 256){
    int row = c >> 4, col8 = (c & 15) * 8;
    *(uint4*)(vals + ((size_t)a * B_N + row0 + row) * H_N + col8) =
        *(const uint4*)&T[row * 136 + col8];
    *(uint4*)(keys + ((size_t)a * B_N + row0 + row) * H_N + col8) =
        *(const uint4*)&T2[row * 136 + col8];
  }
}

// ---------------------------------------------------------------------------
// Attention. LDS tiles permuted at 16B-unit granularity:
//   U(i,bl,k,dg) = (bl*4+dg)*32 + k*8 + (i ^ (k<<1))
// -> si reads perfectly bank-balanced; K/V dot reads are 8-lane broadcasts
// at 2-way (old row-major layout was a 32-way conflict: bank=16k+d2 only).
// Same 24 KB, pure permutation. `other` may alias `keys` (reads complete
// before __syncthreads; rows disjoint across blocks).
// ---------------------------------------------------------------------------
__global__ __launch_bounds__(256) void k_attn(
    const u16* __restrict__ sels, const u16* __restrict__ keys,
    const u16* __restrict__ vals, u16* __restrict__ other)
{
  int b0 = blockIdx.x * 8;
  int t = threadIdx.x;
  __shared__ __align__(16) u16 sS[8192], sK[8192], sV[8192];
  #pragma unroll
  for (int c = t; c < 1024; c += 256){
    int pr = c >> 4, uir = c & 15;
    int aa = pr & 7, bl2 = pr >> 3;
    int kk = uir >> 2, dg = uir & 3;
    int U = (bl2 * 4 + dg) * 32 + kk * 8 + (aa ^ (kk << 1));
    size_t go = ((size_t)aa * B_N + b0 + bl2) * KD_N;
    ((uint4*)sS)[U] = *((const uint4*)(sels + go) + uir);
    ((uint4*)sK)[U] = *((const uint4*)(keys + go) + uir);
    ((uint4*)sV)[U] = *((const uint4*)(vals + go) + uir);
  }
  __syncthreads();
  int i = t & 7, k = (t >> 3) & 3, bl = t >> 5;
  float si[32];
  #pragma unroll
  for (int dg = 0; dg < 4; ++dg){
    int U = (bl * 4 + dg) * 32 + k * 8 + (i ^ (k << 1));
    uint4 s4 = ((const uint4*)sS)[U];
    const u32* sp = (const u32*)&s4;
    #pragma unroll
    for (int jj = 0; jj < 4; ++jj){
      int d2 = dg * 4 + jj;
      si[2 * d2] = bf_lo(sp[jj]); si[2 * d2 + 1] = bf_hi(sp[jj]);
    }
  }
  float lg[8];
  #pragma unroll
  for (int j = 0; j < 8; ++j){
    float acc = 0.f;
    #pragma unroll
    for (int dg = 0; dg < 4; ++dg){
      int U = (bl * 4 + dg) * 32 + k * 8 + (j ^ (k << 1));
      uint4 k4 = ((const uint4*)sK)[U];
      const u32* kp = (const u32*)&k4;
      #pragma unroll
      for (int jj = 0; jj < 4; ++jj){
        int d2 = dg * 4 + jj;
        acc = fmaf(si[2 * d2], bf_lo(kp[jj]), acc);
        acc = fmaf(si[2 * d2 + 1], bf_hi(kp[jj]), acc);
      }
    }
    lg[j] = acc * 0.17677669529663689f;
  }
  float mx = -3.0e38f;
  #pragma unroll
  for (int j = 0; j < 8; ++j) if (j != i) mx = fmaxf(mx, lg[j]);
  float pe[8], se = 0.f;
  #pragma unroll
  for (int j = 0; j < 8; ++j){
    pe[j] = (j == i) ? 0.f : __expf(lg[j] - mx);
    se += pe[j];
  }
  float inv = 1.f / se;
  #pragma unroll
  for (int j = 0; j < 8; ++j) pe[j] *= inv;
  float o0[16], o1[16];
  #pragma unroll
  for (int d2 = 0; d2 < 16; ++d2){ o0[d2] = 0.f; o1[d2] = 0.f; }
  #pragma unroll
  for (int j = 0; j < 8; ++j){
    #pragma unroll
    for (int dg = 0; dg < 4; ++dg){
      int U = (bl * 4 + dg) * 32 + k * 8 + (j ^ (k << 1));
      uint4 v4 = ((const uint4*)sV)[U];
      const u32* vp = (const u32*)&v4;
      #pragma unroll
      for (int jj = 0; jj < 4; ++jj){
        int d2 = dg * 4 + jj;
        o0[d2] = fmaf(pe[j], bf_lo(vp[jj]), o0[d2]);
        o1[d2] = fmaf(pe[j], bf_hi(vp[jj]), o1[d2]);
      }
    }
  }
  __align__(16) u16 ob[32];
  #pragma unroll
  for (int d2 = 0; d2 < 16; ++d2){
    ob[2 * d2] = f2bf(o0[d2]); ob[2 * d2 + 1] = f2bf(o1[d2]);
  }
  uint4* dst = (uint4*)(other + ((size_t)i * B_N + (b0 + bl)) * KD_N + k * 32);
  const uint4* s4o = (const uint4*)ob;
  #pragma unroll
  for (int c = 0; c < 4; ++c) dst[c] = s4o[c];
}

// ---------------------------------------------------------------------------
// Critic: h = lrelu([sa_enc|other] @ c1_w + c1_b); q = h . c2_w + c2_b
// Double-buffered LDS (48 KB, 3 blocks/CU) + counted vmcnt(6) + raw barriers:
// tile k+1's 6 glds stay in flight across both barriers (T3/T4 pattern).
// All tiles swizzle-staged (source-side) + swizzled frag reads.
// ---------------------------------------------------------------------------
__global__ __launch_bounds__(256, 3) void k_critic(
    const u16* __restrict__ sa_enc, const u16* __restrict__ other,
    const u16* __restrict__ c1H, const u16* __restrict__ c1L,
    const float* __restrict__ c1_b,
    const float* __restrict__ c2w, const float* __restrict__ c2b,
    float* __restrict__ qout)
{
  int a = blockIdx.y; int row0 = blockIdx.x * 128; int t = threadIdx.x;
  int lane = t & 63, wave = t >> 6, l16 = lane & 15, quad = lane >> 4;
  __shared__ __align__(16) u16 Buf[2][12288];  // per buf: Xs | Wh | Wl (4096 u16 each)
  floatx4 acc[2][8];
  #pragma unroll
  for (int mt = 0; mt < 2; ++mt)
    #pragma unroll
    for (int nt = 0; nt < 8; ++nt) acc[mt][nt] = (floatx4){0.f,0.f,0.f,0.f};
  const u16* wbh = c1H + (size_t)a * (H_N * CIN_N);
  const u16* wbl = c1L + (size_t)a * (H_N * CIN_N);

  auto stage = [&](int kt, int b){
    const u16* th = wbh + kt * 4096;
    const u16* tl = wbl + kt * 4096;
    const u16* src = (kt < 4) ? sa_enc : other;
    int kb = (kt < 4) ? kt * 32 : kt * 32 - H_N;
    u16* Xs = Buf[b]; u16* Wh = Buf[b] + 4096; u16* Wl = Buf[b] + 8192;
    #pragma unroll
    for (int c = t; c < 512; c += 256){
      glds16(th + swzu(c) * 8, Wh + c * 8);
      glds16(tl + swzu(c) * 8, Wl + c * 8);
      int r = c >> 2, q = (c & 3) ^ ((c >> 3) & 3);
      glds16(src + ((size_t)a * B_N + row0 + r) * H_N + kb + q * 8, Xs + c * 8);
    }
  };

  stage(0, 0);
  asm volatile("" ::: "memory");
  #pragma unroll
  for (int kt = 0; kt < 8; ++kt){
    if (kt < 7){
      stage(kt + 1, (kt + 1) & 1);
      asm volatile("s_waitcnt vmcnt(6)" ::: "memory");   // tile kt's 6 done
    } else {
      asm volatile("s_waitcnt vmcnt(0)" ::: "memory");
    }
    __builtin_amdgcn_s_barrier();
    asm volatile("" ::: "memory");
    {
      const u16* Xs = Buf[kt & 1];
      const u16* Wh = Buf[kt & 1] + 4096;
      const u16* Wl = Buf[kt & 1] + 8192;
      short8 ah[2], bh[8], bl[8];
      #pragma unroll
      for (int mt = 0; mt < 2; ++mt){
        int v = (wave * 32 + mt * 16 + l16) * 4 + quad; v ^= (v >> 3) & 3;
        ah[mt] = *(const short8*)&Xs[v * 8];
      }
      #pragma unroll
      for (int nt = 0; nt < 8; ++nt){
        int v = (nt * 16 + l16) * 4 + quad; v ^= (v >> 3) & 3;
        bh[nt] = *(const short8*)&Wh[v * 8];
        bl[nt] = *(const short8*)&Wl[v * 8];
      }
      #pragma unroll
      for (int mt = 0; mt < 2; ++mt)
        #pragma unroll
        for (int nt = 0; nt < 8; ++nt){
          acc[mt][nt] = __builtin_amdgcn_mfma_f32_16x16x32_bf16(ah[mt], bh[nt], acc[mt][nt], 0,0,0);
          acc[mt][nt] = __builtin_amdgcn_mfma_f32_16x16x32_bf16(ah[mt], bl[nt], acc[mt][nt], 0,0,0);
        }
    }
    hard_barrier();
  }

  float c2r[8], bv[8];
  #pragma unroll
  for (int nt = 0; nt < 8; ++nt){
    c2r[nt] = c2w[a * H_N + nt * 16 + l16];
    bv[nt]  = c1_b[a * H_N + nt * 16 + l16];
  }
  #pragma unroll
  for (int mt = 0; mt < 2; ++mt){
    #pragma unroll
    for (int r = 0; r < 4; ++r){
      float s = 0.f;
      #pragma unroll
      for (int nt = 0; nt < 8; ++nt){
        float h = lrelu(acc[mt][nt][r] + bv[nt]);
        s = fmaf(h, c2r[nt], s);
      }
      s += __shfl_xor(s, 1);
      s += __shfl_xor(s, 2);
      s += __shfl_xor(s, 4);
      s += __shfl_xor(s, 8);
      if (l16 == 0){
        int row = row0 + wave * 32 + mt * 16 + quad * 4 + r;
        qout[(size_t)a * B_N + row] = s + c2b[a];
      }
    }
  }
}

// ---------------------------------------------------------------------------
extern "C" void kernel_launch(void* const* d_in, const int* in_sizes, int n_in,
                              void* d_out, int out_size, void* d_ws, size_t ws_size,
                              hipStream_t stream)
{
  const float* states  = (const float*)d_in[0];
  const float* actions = (const float*)d_in[1];
  const float* enc_w   = (const float*)d_in[2];
  const float* enc_b   = (const float*)d_in[3];
  const float* aenc_w  = (const float*)d_in[4];
  const float* aenc_b  = (const float*)d_in[5];
  const float* key_w   = (const float*)d_in[6];
  const float* sel_w   = (const float*)d_in[7];
  const float* val_w   = (const float*)d_in[8];
  const float* val_b   = (const float*)d_in[9];
  const float* c1_w    = (const float*)d_in[10];
  const float* c1_b    = (const float*)d_in[11];
  const float* c2_w    = (const float*)d_in[12];
  const float* c2_b    = (const float*)d_in[13];
  float* q = (float*)d_out;

  char* ws = (char*)d_ws;
  // Pack region [0, 884,736) overlaps stats partials [0, 1,310,720):
  // stats/finalize consume `part` before k_pack overwrites (sequential stream).
  u16* encH  = (u16*)(ws + 0);          // 327680 B
  u16* encL  = (u16*)(ws + 327680);     // 327680 B
  u16* aencH = (u16*)(ws + 655360);     //  65536 B
  u16* aencL = (u16*)(ws + 720896);     //  65536 B
  u16* keyH  = (u16*)(ws + 786432);     //  32768 B
  u16* selH  = (u16*)(ws + 819200);     //  32768 B
  u16* valH  = (u16*)(ws + 851968);     //  32768 B -> ends 884,736
  float* part    = (float*)ws;          // 1,310,720 B (dead after finalize)
  float* meanArr = (float*)(ws + 1310720);
  float* istdArr = (float*)(ws + 1315840);
  u16* c1H = (u16*)(ws + 1320960);      // 524288 B
  u16* c1L = (u16*)(ws + 1845248);      // 524288 B -> ends 2,369,536
  const size_t ibase = 4194304;
  const size_t BUF = (size_t)A_N * B_N * 128 * 2;   // 64 MB
  u16* sa_enc = (u16*)(ws + ibase);
  u16* sels   = (u16*)(ws + ibase + BUF);
  u16* keys   = (u16*)(ws + ibase + 2 * BUF);       // keys, later `other`
  u16* vals   = (u16*)(ws + ibase + 3 * BUF);

  k_stats<<<dim3(CHUNKS, A_N), 256, 0, stream>>>(states, actions, part);
  k_finalize<<<(A_N * SAF + 255) / 256, 256, 0, stream>>>(part, meanArr, istdArr);
  k_pack<<<(PACK_TOTAL + 255) / 256, 256, 0, stream>>>(
      enc_w, aenc_w, key_w, sel_w, val_w, c1_w,
      encH, encL, aencH, aencL, keyH, selH, valH, c1H, c1L);

  dim3 g(B_N / 128, A_N);
  k_enc_sel<<<g, 256, 0, stream>>>(states, actions, meanArr, istdArr,
                                   encH, encL, enc_b, selH, sa_enc, sels);
  k_aenc_kv<<<g, 256, 0, stream>>>(actions, meanArr, istdArr,
                                   aencH, aencL, aenc_b, keyH, valH, val_b,
                                   keys, vals);
  k_attn<<<B_N / 8, 256, 0, stream>>>(sels, keys, vals, keys);  // other -> keys
  k_critic<<<g, 256, 0, stream>>>(sa_enc, keys, c1H, c1L, c1_b, c2_w, c2_b, q);
}

// Round 3
// 522.468 us; speedup vs baseline: 1.0693x; 1.0693x over previous
//
#include <hip/hip_runtime.h>
#include <hip/hip_bf16.h>
#include <stdint.h>

// Problem constants
#define A_N 8
#define B_N 32768
#define IN_N 128
#define OUT_N 32
#define SAF 160      // IN + OUT  (= enc K, exactly 5 x 32: NO pad)
#define H_N 128
#define D_N 32
#define KD_N 128     // K*D
#define CIN_N 256    // critic input = H + K*D
#define CHUNKS 128   // stats chunks over B
#define EPSV 1e-5f

typedef unsigned int u32;
typedef unsigned short u16;
typedef __attribute__((ext_vector_type(8))) short short8;    // 8 bf16 (4 VGPRs)
typedef __attribute__((ext_vector_type(4))) float floatx4;   // MFMA C/D

// async global->LDS, 16B per lane. LDS dest = wave-uniform base + lane*16,
// so dest layout MUST be linear in lane order.
typedef __attribute__((address_space(1))) void gvoid;
typedef __attribute__((address_space(3))) void lvoid;
__device__ __forceinline__ void glds16(const void* g, void* l){
  __builtin_amdgcn_global_load_lds((gvoid*)g, (lvoid*)l, 16, 0, 0);
}

// 16B-unit XOR swizzle (involution, permutes only within 64B -> global
// coalescing preserved). glds can't scatter its LDS dest, so the swizzle is
// applied on the GLOBAL SOURCE address and again on the frag-read address.
// Verified round 2: enc_sel SQ_LDS_BANK_CONFLICT 6.4M -> 2.75M.
__device__ __forceinline__ int swzu(int u){ return u ^ ((u >> 3) & 3); }

__device__ __forceinline__ float bf_lo(u32 u){ return __uint_as_float(u << 16); }
__device__ __forceinline__ float bf_hi(u32 u){ return __uint_as_float(u & 0xffff0000u); }
__device__ __forceinline__ float bf2f(u16 b){ return __uint_as_float(((u32)b) << 16); }
__device__ __forceinline__ u16 f2bf(float f){
  u32 u = __float_as_uint(f);
  return (u16)((u + 0x7fffu + ((u >> 16) & 1u)) >> 16);
}
__device__ __forceinline__ float lrelu(float x){ return x > 0.f ? x : 0.01f * x; }

// ---------------------------------------------------------------------------
// Stage 1: BN statistics (sum, sumsq) per (agent, feature).
// ---------------------------------------------------------------------------
__global__ __launch_bounds__(256) void k_stats(
    const float* __restrict__ states, const float* __restrict__ actions,
    float* __restrict__ part)
{
  int a = blockIdx.y;
  int chunk = blockIdx.x;
  int t = threadIdx.x;
  int r0 = chunk * (B_N / CHUNKS);   // 256 rows per chunk
  __shared__ float red[512];
  {
    int f = t & 127, half = t >> 7;
    const float* p = states + ((size_t)a * B_N + r0 + half) * IN_N + f;
    float s1 = 0.f, s2 = 0.f;
    for (int it = 0; it < 128; ++it){
      float v = p[(size_t)(2 * it) * IN_N];
      s1 += v; s2 += v * v;
    }
    red[t] = s1; red[256 + t] = s2;
    __syncthreads();
    if (t < 128){
      float a1 = red[t] + red[t + 128];
      float a2 = red[256 + t] + red[256 + t + 128];
      size_t o = (((size_t)a * CHUNKS + chunk) * SAF + t) * 2;
      part[o] = a1; part[o + 1] = a2;
    }
    __syncthreads();
  }
  {
    int f = t & 31, g = t >> 5;
    const float* p = actions + ((size_t)a * B_N + r0 + g) * OUT_N + f;
    float s1 = 0.f, s2 = 0.f;
    for (int it = 0; it < 32; ++it){
      float v = p[(size_t)(8 * it) * OUT_N];
      s1 += v; s2 += v * v;
    }
    red[t] = s1; red[256 + t] = s2;
    __syncthreads();
    if (t < 32){
      float a1 = 0.f, a2 = 0.f;
      #pragma unroll
      for (int gg = 0; gg < 8; ++gg){
        a1 += red[t + 32 * gg];
        a2 += red[256 + t + 32 * gg];
      }
      size_t o = (((size_t)a * CHUNKS + chunk) * SAF + 128 + t) * 2;
      part[o] = a1; part[o + 1] = a2;
    }
  }
}

__global__ void k_finalize(const float* __restrict__ part,
                           float* __restrict__ meanArr, float* __restrict__ istdArr)
{
  int idx = blockIdx.x * blockDim.x + threadIdx.x;
  if (idx >= A_N * SAF) return;
  int a = idx / SAF, f = idx % SAF;
  float s1 = 0.f, s2 = 0.f;
  for (int c = 0; c < CHUNKS; ++c){
    size_t o = (((size_t)a * CHUNKS + c) * SAF + f) * 2;
    s1 += part[o]; s2 += part[o + 1];
  }
  float m = s1 * (1.f / B_N);
  float v = s2 * (1.f / B_N) - m * m;
  if (v < 0.f) v = 0.f;
  meanArr[idx] = m;
  istdArr[idx] = rsqrtf(v + EPSV);
}

// ---------------------------------------------------------------------------
// Weight pre-pack, TILE-MAJOR for global_load_lds:
//   layout = [k-tile][128 n][32 k] contiguous (4096 u16 = 8192 B per tile).
// enc/c1: hi/lo bf16 pairs; key/sel/val: single bf16.
// ---------------------------------------------------------------------------
__device__ __forceinline__ void packpair(float w, u16* __restrict__ dh,
                                         u16* __restrict__ dl, int i){
  u16 h = f2bf(w);
  dh[i] = h;
  dl[i] = f2bf(w - bf2f(h));
}

__global__ __launch_bounds__(256) void k_pack(
    const float* __restrict__ enc_w, const float* __restrict__ aenc_w,
    const float* __restrict__ key_w, const float* __restrict__ sel_w,
    const float* __restrict__ val_w, const float* __restrict__ c1_w,
    u16* __restrict__ encH, u16* __restrict__ encL,
    u16* __restrict__ aencH, u16* __restrict__ aencL,
    u16* __restrict__ keyH, u16* __restrict__ selH, u16* __restrict__ valH,
    u16* __restrict__ c1H, u16* __restrict__ c1L)
{
  int i = blockIdx.x * 256 + threadIdx.x;
  const int S0 = A_N * H_N * SAF;      // 163840 enc (5 tiles/agent)
  const int S1 = A_N * H_N * OUT_N;    // 32768 aenc
  const int S2 = KD_N * H_N;           // 16384 per key/sel/val (4 tiles)
  const int S5 = A_N * H_N * CIN_N;    // 262144 c1 (8 tiles/agent)
  if (i < S0){
    int a = i / (H_N * SAF); int r = i % (H_N * SAF);
    int tile = r >> 12; int rr = r & 4095;
    int n = rr >> 5; int kk = rr & 31;
    int kg = tile * 32 + kk;
    packpair(enc_w[((size_t)a * SAF + kg) * H_N + n], encH, encL, i);
    return;
  }
  i -= S0;
  if (i < S1){
    int a = i >> 12; int rr = i & 4095;
    int n = rr >> 5; int k = rr & 31;
    packpair(aenc_w[((size_t)a * OUT_N + k) * H_N + n], aencH, aencL, i);
    return;
  }
  i -= S1;
  if (i < 3 * S2){
    int which = i / S2; int j = i % S2;
    int tile = j >> 12; int rr = j & 4095;
    int n = rr >> 5; int kk = rr & 31;
    int kg = tile * 32 + kk;
    const float* w = (which == 0) ? key_w : ((which == 1) ? sel_w : val_w);
    u16* dh = (which == 0) ? keyH : ((which == 1) ? selH : valH);
    dh[j] = f2bf(w[(((size_t)(n >> 5)) * H_N + kg) * D_N + (n & 31)]);
    return;
  }
  i -= 3 * S2;
  if (i < S5){
    int a = i >> 15; int r = i & 32767;
    int tile = r >> 12; int rr = r & 4095;
    int n = rr >> 5; int kk = rr & 31;
    int kg = tile * 32 + kk;
    packpair(c1_w[((size_t)a * CIN_N + kg) * H_N + n], c1H, c1L, i);
  }
}
#define PACK_TOTAL (A_N*H_N*SAF + A_N*H_N*OUT_N + 3*KD_N*H_N + A_N*H_N*CIN_N)

// ---------------------------------------------------------------------------
// Fused kernel 1: sa_enc = lrelu(BN(concat) @ enc_w + enc_b)  [3-term, BK=32,
//   K=160], sels = sa_enc @ sel_w [1-term, BK=64].
// Round-1 synchronous structure (no reg-pipeline: it spilled in round 2);
// weight tiles swizzle-staged + swizzled frag reads.
// ---------------------------------------------------------------------------
__global__ __launch_bounds__(256, 3) void k_enc_sel(
    const float* __restrict__ states, const float* __restrict__ actions,
    const float* __restrict__ mean, const float* __restrict__ istd,
    const u16* __restrict__ encH, const u16* __restrict__ encL,
    const float* __restrict__ enc_b,
    const u16* __restrict__ selH,
    u16* __restrict__ sa_enc, u16* __restrict__ sels)
{
  int a = blockIdx.y; int row0 = blockIdx.x * 128; int t = threadIdx.x;
  int lane = t & 63, wave = t >> 6, l16 = lane & 15, quad = lane >> 4;
  __shared__ __align__(16) u16 S[25600];
  __shared__ __align__(16) float sc[160], sh[160];
  u16* Wh = S;            // [128][32] enc weight hi tile (phase 1)
  u16* Wl = S + 4096;     // [128][32]
  u16* Xh = S + 8192;     // [128][40]
  u16* Xl = S + 13312;    // [128][40]
  u16* T  = S;            // [128][136] (phase-1 output / phase-2 A)
  u16* Ws = S + 17408;    // [2][128][32] sel weight tiles (phase 2)

  if (t < SAF){
    float m = mean[a * SAF + t], s = istd[a * SAF + t];
    sc[t] = s; sh[t] = -m * s;
  }
  floatx4 acc[2][8];
  #pragma unroll
  for (int mt = 0; mt < 2; ++mt)
    #pragma unroll
    for (int nt = 0; nt < 8; ++nt) acc[mt][nt] = (floatx4){0.f,0.f,0.f,0.f};
  const u16* ebh = encH + (size_t)a * (H_N * SAF);
  const u16* ebl = encL + (size_t)a * (H_N * SAF);
  __syncthreads();

  // ---- phase 1: enc GEMM (3-term split), K=160, BK=32 ----
  for (int k0 = 0; k0 < SAF; k0 += 32){
    const u16* th = ebh + (k0 >> 5) * 4096;
    const u16* tl = ebl + (k0 >> 5) * 4096;
    #pragma unroll
    for (int c = t; c < 512; c += 256){
      glds16(th + swzu(c) * 8, Wh + c * 8);
      glds16(tl + swzu(c) * 8, Wl + c * 8);
    }
    for (int c = t; c < 1024; c += 256){
      int r = c >> 3, kc = (c & 7) * 4, f = k0 + kc;
      size_t row = (size_t)a * B_N + row0 + r;
      float4 v;
      if (f < IN_N) v = *(const float4*)(states + row * IN_N + f);
      else          v = *(const float4*)(actions + row * OUT_N + (f - IN_N));
      float4 scv = *(const float4*)&sc[f];
      float4 shv = *(const float4*)&sh[f];
      float x0 = fmaf(v.x, scv.x, shv.x), x1 = fmaf(v.y, scv.y, shv.y);
      float x2 = fmaf(v.z, scv.z, shv.z), x3 = fmaf(v.w, scv.w, shv.w);
      u16 h0 = f2bf(x0), h1 = f2bf(x1), h2 = f2bf(x2), h3 = f2bf(x3);
      uint2 hv; hv.x = (u32)h0 | ((u32)h1 << 16); hv.y = (u32)h2 | ((u32)h3 << 16);
      *(uint2*)&Xh[r * 40 + kc] = hv;
      u16 l0 = f2bf(x0 - bf2f(h0)), l1 = f2bf(x1 - bf2f(h1));
      u16 l2 = f2bf(x2 - bf2f(h2)), l3 = f2bf(x3 - bf2f(h3));
      uint2 lv; lv.x = (u32)l0 | ((u32)l1 << 16); lv.y = (u32)l2 | ((u32)l3 << 16);
      *(uint2*)&Xl[r * 40 + kc] = lv;
    }
    __syncthreads();
    {
      short8 ah[2], al[2], bh[8], bl[8];
      #pragma unroll
      for (int mt = 0; mt < 2; ++mt){
        int rr = (wave * 32 + mt * 16 + l16) * 40 + quad * 8;
        ah[mt] = *(const short8*)&Xh[rr];
        al[mt] = *(const short8*)&Xl[rr];
      }
      #pragma unroll
      for (int nt = 0; nt < 8; ++nt){
        int v = (nt * 16 + l16) * 4 + quad; v ^= (v >> 3) & 3;
        bh[nt] = *(const short8*)&Wh[v * 8];
        bl[nt] = *(const short8*)&Wl[v * 8];
      }
      #pragma unroll
      for (int mt = 0; mt < 2; ++mt)
        #pragma unroll
        for (int nt = 0; nt < 8; ++nt){
          acc[mt][nt] = __builtin_amdgcn_mfma_f32_16x16x32_bf16(ah[mt], bh[nt], acc[mt][nt], 0,0,0);
          acc[mt][nt] = __builtin_amdgcn_mfma_f32_16x16x32_bf16(ah[mt], bl[nt], acc[mt][nt], 0,0,0);
          acc[mt][nt] = __builtin_amdgcn_mfma_f32_16x16x32_bf16(al[mt], bh[nt], acc[mt][nt], 0,0,0);
        }
    }
    __syncthreads();
  }

  // ---- phase-1 epilogue: lrelu+bias -> bf16 tile T in LDS ----
  {
    float bv[8];
    #pragma unroll
    for (int nt = 0; nt < 8; ++nt) bv[nt] = enc_b[a * H_N + nt * 16 + l16];
    #pragma unroll
    for (int mt = 0; mt < 2; ++mt)
      #pragma unroll
      for (int nt = 0; nt < 8; ++nt)
        #pragma unroll
        for (int r = 0; r < 4; ++r){
          int rl = wave * 32 + mt * 16 + quad * 4 + r;
          T[rl * 136 + nt * 16 + l16] = f2bf(lrelu(acc[mt][nt][r] + bv[nt]));
        }
  }
  __syncthreads();
  // vectorized sa_enc store from tile
  for (int c = t; c < 2048; c += 256){
    int row = c >> 4, col8 = (c & 15) * 8;
    *(uint4*)(sa_enc + ((size_t)a * B_N + row0 + row) * H_N + col8) =
        *(const uint4*)&T[row * 136 + col8];
  }

  // ---- phase 2: sels = T @ selT (single-term), BK=64 ----
  #pragma unroll
  for (int mt = 0; mt < 2; ++mt)
    #pragma unroll
    for (int nt = 0; nt < 8; ++nt) acc[mt][nt] = (floatx4){0.f,0.f,0.f,0.f};
  for (int k0 = 0; k0 < H_N; k0 += 64){
    #pragma unroll
    for (int c = t; c < 1024; c += 256)
      glds16(selH + (k0 >> 5) * 4096 + swzu(c) * 8, Ws + c * 8);
    __syncthreads();
    #pragma unroll
    for (int ks = 0; ks < 64; ks += 32){
      short8 ah[2], bh[8];
      #pragma unroll
      for (int mt = 0; mt < 2; ++mt)
        ah[mt] = *(const short8*)&T[(wave * 32 + mt * 16 + l16) * 136 + k0 + ks + quad * 8];
      #pragma unroll
      for (int nt = 0; nt < 8; ++nt){
        int v = ((ks >> 5) << 9) + (nt * 16 + l16) * 4 + quad; v ^= (v >> 3) & 3;
        bh[nt] = *(const short8*)&Ws[v * 8];
      }
      #pragma unroll
      for (int mt = 0; mt < 2; ++mt)
        #pragma unroll
        for (int nt = 0; nt < 8; ++nt)
          acc[mt][nt] = __builtin_amdgcn_mfma_f32_16x16x32_bf16(ah[mt], bh[nt], acc[mt][nt], 0,0,0);
    }
    __syncthreads();
  }
  #pragma unroll
  for (int mt = 0; mt < 2; ++mt)
    #pragma unroll
    for (int nt = 0; nt < 8; ++nt)
      #pragma unroll
      for (int r = 0; r < 4; ++r){
        int rl = wave * 32 + mt * 16 + quad * 4 + r;
        T[rl * 136 + nt * 16 + l16] = f2bf(acc[mt][nt][r]);
      }
  __syncthreads();
  for (int c = t; c < 2048; c += 256){
    int row = c >> 4, col8 = (c & 15) * 8;
    *(uint4*)(sels + ((size_t)a * B_N + row0 + row) * H_N + col8) =
        *(const uint4*)&T[row * 136 + col8];
  }
}

// ---------------------------------------------------------------------------
// Fused kernel 2: a_enc = lrelu(BN(actions) @ aenc_w + aenc_b) [3-term, K=32]
//   keys & vals in ONE dual-accumulator loop (weights swizzle-staged).
// ---------------------------------------------------------------------------
__global__ __launch_bounds__(256, 2) void k_aenc_kv(
    const float* __restrict__ actions,
    const float* __restrict__ mean, const float* __restrict__ istd,
    const u16* __restrict__ aencH, const u16* __restrict__ aencL,
    const float* __restrict__ aenc_b,
    const u16* __restrict__ keyH, const u16* __restrict__ valH,
    const float* __restrict__ val_b,
    u16* __restrict__ keys, u16* __restrict__ vals)
{
  int a = blockIdx.y; int row0 = blockIdx.x * 128; int t = threadIdx.x;
  int lane = t & 63, wave = t >> 6, l16 = lane & 15, quad = lane >> 4;
  __shared__ __align__(16) u16 S[34816];
  __shared__ __align__(16) float sc[32], sh[32];
  u16* T  = S;            // [128][136] a_enc tile; later vals tile
  u16* WK = S + 17408;    // [2][128][32] key weight tiles
  u16* WV = S + 25600;    // [2][128][32] val weight tiles
  u16* T2 = S + 17408;    // [128][136] keys tile (epilogue)

  if (t < 32){
    float m = mean[a * SAF + 128 + t], s = istd[a * SAF + 128 + t];
    sc[t] = s; sh[t] = -m * s;
  }
  floatx4 accK[2][8], accV[2][8];
  #pragma unroll
  for (int mt = 0; mt < 2; ++mt)
    #pragma unroll
    for (int nt = 0; nt < 8; ++nt){
      accK[mt][nt] = (floatx4){0.f,0.f,0.f,0.f};
      accV[mt][nt] = (floatx4){0.f,0.f,0.f,0.f};
    }
  __syncthreads();

  // ---- phase 1: aenc GEMM, K=32 single tile ----
  {
    u16* Wh1 = S;  u16* Wl1 = S + 4096;
    u16* Xh = S + 8192; u16* Xl = S + 13312;  // [128][40]
    const u16* abh = aencH + (size_t)a * 4096;
    const u16* abl = aencL + (size_t)a * 4096;
    #pragma unroll
    for (int c = t; c < 512; c += 256){
      glds16(abh + swzu(c) * 8, Wh1 + c * 8);
      glds16(abl + swzu(c) * 8, Wl1 + c * 8);
    }
    for (int c = t; c < 1024; c += 256){
      int r = c >> 3, kc = (c & 7) * 4;
      size_t row = (size_t)a * B_N + row0 + r;
      float4 v = *(const float4*)(actions + row * OUT_N + kc);
      float4 scv = *(const float4*)&sc[kc];
      float4 shv = *(const float4*)&sh[kc];
      float x0 = fmaf(v.x, scv.x, shv.x), x1 = fmaf(v.y, scv.y, shv.y);
      float x2 = fmaf(v.z, scv.z, shv.z), x3 = fmaf(v.w, scv.w, shv.w);
      u16 h0 = f2bf(x0), h1 = f2bf(x1), h2 = f2bf(x2), h3 = f2bf(x3);
      uint2 hv; hv.x = (u32)h0 | ((u32)h1 << 16); hv.y = (u32)h2 | ((u32)h3 << 16);
      *(uint2*)&Xh[r * 40 + kc] = hv;
      u16 l0 = f2bf(x0 - bf2f(h0)), l1 = f2bf(x1 - bf2f(h1));
      u16 l2 = f2bf(x2 - bf2f(h2)), l3 = f2bf(x3 - bf2f(h3));
      uint2 lv; lv.x = (u32)l0 | ((u32)l1 << 16); lv.y = (u32)l2 | ((u32)l3 << 16);
      *(uint2*)&Xl[r * 40 + kc] = lv;
    }
    __syncthreads();
    short8 ah[2], al[2], bh[8], bl[8];
    #pragma unroll
    for (int mt = 0; mt < 2; ++mt){
      int rr = (wave * 32 + mt * 16 + l16) * 40 + quad * 8;
      ah[mt] = *(const short8*)&Xh[rr];
      al[mt] = *(const short8*)&Xl[rr];
    }
    #pragma unroll
    for (int nt = 0; nt < 8; ++nt){
      int v = (nt * 16 + l16) * 4 + quad; v ^= (v >> 3) & 3;
      bh[nt] = *(const short8*)&Wh1[v * 8];
      bl[nt] = *(const short8*)&Wl1[v * 8];
    }
    #pragma unroll
    for (int mt = 0; mt < 2; ++mt)
      #pragma unroll
      for (int nt = 0; nt < 8; ++nt){
        accK[mt][nt] = __builtin_amdgcn_mfma_f32_16x16x32_bf16(ah[mt], bh[nt], accK[mt][nt], 0,0,0);
        accK[mt][nt] = __builtin_amdgcn_mfma_f32_16x16x32_bf16(ah[mt], bl[nt], accK[mt][nt], 0,0,0);
        accK[mt][nt] = __builtin_amdgcn_mfma_f32_16x16x32_bf16(al[mt], bh[nt], accK[mt][nt], 0,0,0);
      }
    __syncthreads();
  }
  // a_enc -> LDS tile T; move from accK, then zero accK
  {
    float bv[8];
    #pragma unroll
    for (int nt = 0; nt < 8; ++nt) bv[nt] = aenc_b[a * H_N + nt * 16 + l16];
    #pragma unroll
    for (int mt = 0; mt < 2; ++mt)
      #pragma unroll
      for (int nt = 0; nt < 8; ++nt){
        #pragma unroll
        for (int r = 0; r < 4; ++r){
          int rl = wave * 32 + mt * 16 + quad * 4 + r;
          T[rl * 136 + nt * 16 + l16] = f2bf(lrelu(accK[mt][nt][r] + bv[nt]));
        }
        accK[mt][nt] = (floatx4){0.f,0.f,0.f,0.f};
      }
  }

  // ---- phase 2: keys + vals in one dual-acc loop (BK=64, single-term) ----
  for (int k0 = 0; k0 < H_N; k0 += 64){
    __syncthreads();
    #pragma unroll
    for (int c = t; c < 1024; c += 256){
      glds16(keyH + (k0 >> 5) * 4096 + swzu(c) * 8, WK + c * 8);
      glds16(valH + (k0 >> 5) * 4096 + swzu(c) * 8, WV + c * 8);
    }
    __syncthreads();
    #pragma unroll
    for (int ks = 0; ks < 64; ks += 32){
      short8 ah[2], bk[8], bv[8];
      #pragma unroll
      for (int mt = 0; mt < 2; ++mt)
        ah[mt] = *(const short8*)&T[(wave * 32 + mt * 16 + l16) * 136 + k0 + ks + quad * 8];
      #pragma unroll
      for (int nt = 0; nt < 8; ++nt){
        int v = ((ks >> 5) << 9) + (nt * 16 + l16) * 4 + quad; v ^= (v >> 3) & 3;
        bk[nt] = *(const short8*)&WK[v * 8];
        bv[nt] = *(const short8*)&WV[v * 8];
      }
      #pragma unroll
      for (int mt = 0; mt < 2; ++mt)
        #pragma unroll
        for (int nt = 0; nt < 8; ++nt){
          accK[mt][nt] = __builtin_amdgcn_mfma_f32_16x16x32_bf16(ah[mt], bk[nt], accK[mt][nt], 0,0,0);
          accV[mt][nt] = __builtin_amdgcn_mfma_f32_16x16x32_bf16(ah[mt], bv[nt], accV[mt][nt], 0,0,0);
        }
    }
  }
  __syncthreads();
  // epilogue: vals -> T (with bias+lrelu), keys -> T2; both vectorized
  {
    float bv[8];
    #pragma unroll
    for (int nt = 0; nt < 8; ++nt) bv[nt] = val_b[nt * 16 + l16];
    #pragma unroll
    for (int mt = 0; mt < 2; ++mt)
      #pragma unroll
      for (int nt = 0; nt < 8; ++nt)
        #pragma unroll
        for (int r = 0; r < 4; ++r){
          int rl = wave * 32 + mt * 16 + quad * 4 + r;
          T[rl * 136 + nt * 16 + l16]  = f2bf(lrelu(accV[mt][nt][r] + bv[nt]));
          T2[rl * 136 + nt * 16 + l16] = f2bf(accK[mt][nt][r]);
        }
  }
  __syncthreads();
  for (int c = t; c < 2048; c += 256){
    int row = c >> 4, col8 = (c & 15) * 8;
    *(uint4*)(vals + ((size_t)a * B_N + row0 + row) * H_N + col8) =
        *(const uint4*)&T[row * 136 + col8];
    *(uint4*)(keys + ((size_t)a * B_N + row0 + row) * H_N + col8) =
        *(const uint4*)&T2[row * 136 + col8];
  }
}

// ---------------------------------------------------------------------------
// Attention. LDS tiles permuted at 16B-unit granularity:
//   U(aa,bl,kk,dg) = (bl*4+dg)*32 + kk*8 + (aa ^ (kk<<1) ^ dg)
// Old row-major layout made the si gather a 32-way bank conflict (bank =
// 16k+d2, independent of lane's agent index). Permuted: staging writes and
// K/V dot reads 2-way (free). Same 24 KB, pure permutation. `other` may
// alias `keys` (reads complete before __syncthreads; rows disjoint).
// ---------------------------------------------------------------------------
__global__ __launch_bounds__(256) void k_attn(
    const u16* __restrict__ sels, const u16* __restrict__ keys,
    const u16* __restrict__ vals, u16* __restrict__ other)
{
  int b0 = blockIdx.x * 8;
  int t = threadIdx.x;
  __shared__ __align__(16) u16 sS[8192], sK[8192], sV[8192];
  #pragma unroll
  for (int c = t; c < 1024; c += 256){
    int pr = c >> 4, uir = c & 15;
    int aa = pr & 7, bl2 = pr >> 3;
    int kk = uir >> 2, dg = uir & 3;
    int U = (bl2 * 4 + dg) * 32 + kk * 8 + (aa ^ (kk << 1) ^ dg);
    size_t go = ((size_t)aa * B_N + b0 + bl2) * KD_N;
    ((uint4*)sS)[U] = *((const uint4*)(sels + go) + uir);
    ((uint4*)sK)[U] = *((const uint4*)(keys + go) + uir);
    ((uint4*)sV)[U] = *((const uint4*)(vals + go) + uir);
  }
  __syncthreads();
  int i = t & 7, k = (t >> 3) & 3, bl = t >> 5;
  float si[32];
  #pragma unroll
  for (int dg = 0; dg < 4; ++dg){
    int U = (bl * 4 + dg) * 32 + k * 8 + (i ^ (k << 1) ^ dg);
    uint4 s4 = ((const uint4*)sS)[U];
    const u32* sp = (const u32*)&s4;
    #pragma unroll
    for (int jj = 0; jj < 4; ++jj){
      int d2 = dg * 4 + jj;
      si[2 * d2] = bf_lo(sp[jj]); si[2 * d2 + 1] = bf_hi(sp[jj]);
    }
  }
  float lg[8];
  #pragma unroll
  for (int j = 0; j < 8; ++j){
    float acc = 0.f;
    #pragma unroll
    for (int dg = 0; dg < 4; ++dg){
      int U = (bl * 4 + dg) * 32 + k * 8 + (j ^ (k << 1) ^ dg);
      uint4 k4 = ((const uint4*)sK)[U];
      const u32* kp = (const u32*)&k4;
      #pragma unroll
      for (int jj = 0; jj < 4; ++jj){
        int d2 = dg * 4 + jj;
        acc = fmaf(si[2 * d2], bf_lo(kp[jj]), acc);
        acc = fmaf(si[2 * d2 + 1], bf_hi(kp[jj]), acc);
      }
    }
    lg[j] = acc * 0.17677669529663689f;
  }
  float mx = -3.0e38f;
  #pragma unroll
  for (int j = 0; j < 8; ++j) if (j != i) mx = fmaxf(mx, lg[j]);
  float pe[8], se = 0.f;
  #pragma unroll
  for (int j = 0; j < 8; ++j){
    pe[j] = (j == i) ? 0.f : __expf(lg[j] - mx);
    se += pe[j];
  }
  float inv = 1.f / se;
  #pragma unroll
  for (int j = 0; j < 8; ++j) pe[j] *= inv;
  float o0[16], o1[16];
  #pragma unroll
  for (int d2 = 0; d2 < 16; ++d2){ o0[d2] = 0.f; o1[d2] = 0.f; }
  #pragma unroll
  for (int j = 0; j < 8; ++j){
    #pragma unroll
    for (int dg = 0; dg < 4; ++dg){
      int U = (bl * 4 + dg) * 32 + k * 8 + (j ^ (k << 1) ^ dg);
      uint4 v4 = ((const uint4*)sV)[U];
      const u32* vp = (const u32*)&v4;
      #pragma unroll
      for (int jj = 0; jj < 4; ++jj){
        int d2 = dg * 4 + jj;
        o0[d2] = fmaf(pe[j], bf_lo(vp[jj]), o0[d2]);
        o1[d2] = fmaf(pe[j], bf_hi(vp[jj]), o1[d2]);
      }
    }
  }
  __align__(16) u16 ob[32];
  #pragma unroll
  for (int d2 = 0; d2 < 16; ++d2){
    ob[2 * d2] = f2bf(o0[d2]); ob[2 * d2 + 1] = f2bf(o1[d2]);
  }
  uint4* dst = (uint4*)(other + ((size_t)i * B_N + (b0 + bl)) * KD_N + k * 32);
  const uint4* s4o = (const uint4*)ob;
  #pragma unroll
  for (int c = 0; c < 4; ++c) dst[c] = s4o[c];
}

// ---------------------------------------------------------------------------
// Critic: h = lrelu([sa_enc|other] @ c1_w + c1_b); q = h . c2_w + c2_b
// Round-1 synchronous single-buffer structure (double-buffer+vmcnt spilled
// in round 2); ALL staging via glds into swizzle-staged stride-32 tiles.
// LDS 24576 B.
// ---------------------------------------------------------------------------
__global__ __launch_bounds__(256, 3) void k_critic(
    const u16* __restrict__ sa_enc, const u16* __restrict__ other,
    const u16* __restrict__ c1H, const u16* __restrict__ c1L,
    const float* __restrict__ c1_b,
    const float* __restrict__ c2w, const float* __restrict__ c2b,
    float* __restrict__ qout)
{
  int a = blockIdx.y; int row0 = blockIdx.x * 128; int t = threadIdx.x;
  int lane = t & 63, wave = t >> 6, l16 = lane & 15, quad = lane >> 4;
  __shared__ __align__(16) u16 Xs[4096];
  __shared__ __align__(16) u16 Wh[4096];
  __shared__ __align__(16) u16 Wl[4096];
  floatx4 acc[2][8];
  #pragma unroll
  for (int mt = 0; mt < 2; ++mt)
    #pragma unroll
    for (int nt = 0; nt < 8; ++nt) acc[mt][nt] = (floatx4){0.f,0.f,0.f,0.f};
  const u16* wbh = c1H + (size_t)a * (H_N * CIN_N);
  const u16* wbl = c1L + (size_t)a * (H_N * CIN_N);

  for (int kt = 0; kt < 8; ++kt){
    const u16* th = wbh + kt * 4096;
    const u16* tl = wbl + kt * 4096;
    #pragma unroll
    for (int c = t; c < 512; c += 256){
      glds16(th + swzu(c) * 8, Wh + c * 8);
      glds16(tl + swzu(c) * 8, Wl + c * 8);
    }
    {
      const u16* src = (kt < 4) ? sa_enc : other;
      int kb = (kt < 4) ? kt * 32 : kt * 32 - H_N;
      #pragma unroll
      for (int c = t; c < 512; c += 256){
        int r = c >> 2, qq = (c & 3) ^ ((c >> 3) & 3);
        glds16(src + ((size_t)a * B_N + row0 + r) * H_N + kb + qq * 8, Xs + c * 8);
      }
    }
    __syncthreads();
    {
      short8 ah[2], bh[8], bl[8];
      #pragma unroll
      for (int mt = 0; mt < 2; ++mt){
        int v = (wave * 32 + mt * 16 + l16) * 4 + quad; v ^= (v >> 3) & 3;
        ah[mt] = *(const short8*)&Xs[v * 8];
      }
      #pragma unroll
      for (int nt = 0; nt < 8; ++nt){
        int v = (nt * 16 + l16) * 4 + quad; v ^= (v >> 3) & 3;
        bh[nt] = *(const short8*)&Wh[v * 8];
        bl[nt] = *(const short8*)&Wl[v * 8];
      }
      #pragma unroll
      for (int mt = 0; mt < 2; ++mt)
        #pragma unroll
        for (int nt = 0; nt < 8; ++nt){
          acc[mt][nt] = __builtin_amdgcn_mfma_f32_16x16x32_bf16(ah[mt], bh[nt], acc[mt][nt], 0,0,0);
          acc[mt][nt] = __builtin_amdgcn_mfma_f32_16x16x32_bf16(ah[mt], bl[nt], acc[mt][nt], 0,0,0);
        }
    }
    __syncthreads();
  }

  float c2r[8], bv[8];
  #pragma unroll
  for (int nt = 0; nt < 8; ++nt){
    c2r[nt] = c2w[a * H_N + nt * 16 + l16];
    bv[nt]  = c1_b[a * H_N + nt * 16 + l16];
  }
  #pragma unroll
  for (int mt = 0; mt < 2; ++mt){
    #pragma unroll
    for (int r = 0; r < 4; ++r){
      float s = 0.f;
      #pragma unroll
      for (int nt = 0; nt < 8; ++nt){
        float h = lrelu(acc[mt][nt][r] + bv[nt]);
        s = fmaf(h, c2r[nt], s);
      }
      s += __shfl_xor(s, 1);
      s += __shfl_xor(s, 2);
      s += __shfl_xor(s, 4);
      s += __shfl_xor(s, 8);
      if (l16 == 0){
        int row = row0 + wave * 32 + mt * 16 + quad * 4 + r;
        qout[(size_t)a * B_N + row] = s + c2b[a];
      }
    }
  }
}

// ---------------------------------------------------------------------------
extern "C" void kernel_launch(void* const* d_in, const int* in_sizes, int n_in,
                              void* d_out, int out_size, void* d_ws, size_t ws_size,
                              hipStream_t stream)
{
  const float* states  = (const float*)d_in[0];
  const float* actions = (const float*)d_in[1];
  const float* enc_w   = (const float*)d_in[2];
  const float* enc_b   = (const float*)d_in[3];
  const float* aenc_w  = (const float*)d_in[4];
  const float* aenc_b  = (const float*)d_in[5];
  const float* key_w   = (const float*)d_in[6];
  const float* sel_w   = (const float*)d_in[7];
  const float* val_w   = (const float*)d_in[8];
  const float* val_b   = (const float*)d_in[9];
  const float* c1_w    = (const float*)d_in[10];
  const float* c1_b    = (const float*)d_in[11];
  const float* c2_w    = (const float*)d_in[12];
  const float* c2_b    = (const float*)d_in[13];
  float* q = (float*)d_out;

  char* ws = (char*)d_ws;
  // Pack region [0, 884,736) overlaps stats partials [0, 1,310,720):
  // stats/finalize consume `part` before k_pack overwrites (sequential stream).
  u16* encH  = (u16*)(ws + 0);          // 327680 B
  u16* encL  = (u16*)(ws + 327680);     // 327680 B
  u16* aencH = (u16*)(ws + 655360);     //  65536 B
  u16* aencL = (u16*)(ws + 720896);     //  65536 B
  u16* keyH  = (u16*)(ws + 786432);     //  32768 B
  u16* selH  = (u16*)(ws + 819200);     //  32768 B
  u16* valH  = (u16*)(ws + 851968);     //  32768 B -> ends 884,736
  float* part    = (float*)ws;          // 1,310,720 B (dead after finalize)
  float* meanArr = (float*)(ws + 1310720);
  float* istdArr = (float*)(ws + 1315840);
  u16* c1H = (u16*)(ws + 1320960);      // 524288 B
  u16* c1L = (u16*)(ws + 1845248);      // 524288 B -> ends 2,369,536
  const size_t ibase = 4194304;
  const size_t BUF = (size_t)A_N * B_N * 128 * 2;   // 64 MB
  u16* sa_enc = (u16*)(ws + ibase);
  u16* sels   = (u16*)(ws + ibase + BUF);
  u16* keys   = (u16*)(ws + ibase + 2 * BUF);       // keys, later `other`
  u16* vals   = (u16*)(ws + ibase + 3 * BUF);

  k_stats<<<dim3(CHUNKS, A_N), 256, 0, stream>>>(states, actions, part);
  k_finalize<<<(A_N * SAF + 255) / 256, 256, 0, stream>>>(part, meanArr, istdArr);
  k_pack<<<(PACK_TOTAL + 255) / 256, 256, 0, stream>>>(
      enc_w, aenc_w, key_w, sel_w, val_w, c1_w,
      encH, encL, aencH, aencL, keyH, selH, valH, c1H, c1L);

  dim3 g(B_N / 128, A_N);
  k_enc_sel<<<g, 256, 0, stream>>>(states, actions, meanArr, istdArr,
                                   encH, encL, enc_b, selH, sa_enc, sels);
  k_aenc_kv<<<g, 256, 0, stream>>>(actions, meanArr, istdArr,
                                   aencH, aencL, aenc_b, keyH, valH, val_b,
                                   keys, vals);
  k_attn<<<B_N / 8, 256, 0, stream>>>(sels, keys, vals, keys);  // other -> keys
  k_critic<<<g, 256, 0, stream>>>(sa_enc, keys, c1H, c1L, c1_b, c2_w, c2_b, q);
}

// Round 4
// 509.536 us; speedup vs baseline: 1.0964x; 1.0254x over previous
//
#include <hip/hip_runtime.h>
#include <hip/hip_bf16.h>
#include <stdint.h>

// Problem constants
#define A_N 8
#define B_N 32768
#define IN_N 128
#define OUT_N 32
#define SAF 160      // IN + OUT  (= enc K, exactly 5 x 32: NO pad)
#define H_N 128
#define D_N 32
#define KD_N 128     // K*D
#define CIN_N 256    // critic input = H + K*D
#define CHUNKS 128   // stats chunks over B
#define EPSV 1e-5f

typedef unsigned int u32;
typedef unsigned short u16;
typedef __attribute__((ext_vector_type(8))) short short8;    // 8 bf16 (4 VGPRs)
typedef __attribute__((ext_vector_type(4))) float floatx4;   // MFMA C/D

// async global->LDS, 16B per lane. LDS dest = wave-uniform base + lane*16,
// so dest layout MUST be linear in lane order. Source addresses kept LINEAR
// (round 3 showed permuted per-lane sources defeat VMEM coalescing: +23us).
typedef __attribute__((address_space(1))) void gvoid;
typedef __attribute__((address_space(3))) void lvoid;
__device__ __forceinline__ void glds16(const void* g, void* l){
  __builtin_amdgcn_global_load_lds((gvoid*)g, (lvoid*)l, 16, 0, 0);
}

// 16B-unit XOR swizzle (involution). The permutation is BAKED INTO THE PACKED
// GLOBAL LAYOUT (k_pack writes unit u at position swzu(u) within each
// 512-unit tile), so staging is linear glds and LDS ends up holding the
// conflict-free layout; frag reads apply the same XOR to find logical units.
// Verified round 2/3: enc_sel SQ_LDS_BANK_CONFLICT 6.4M -> 2.75M.
__device__ __forceinline__ int swzu(int u){ return u ^ ((u >> 3) & 3); }
// element-level version for k_pack (rr in [0,4096) within a tile)
__device__ __forceinline__ int swzi(int rr){
  int u = rr >> 3;
  u ^= (u >> 3) & 3;
  return (u << 3) | (rr & 7);
}

__device__ __forceinline__ float bf_lo(u32 u){ return __uint_as_float(u << 16); }
__device__ __forceinline__ float bf_hi(u32 u){ return __uint_as_float(u & 0xffff0000u); }
__device__ __forceinline__ float bf2f(u16 b){ return __uint_as_float(((u32)b) << 16); }
__device__ __forceinline__ u16 f2bf(float f){
  u32 u = __float_as_uint(f);
  return (u16)((u + 0x7fffu + ((u >> 16) & 1u)) >> 16);
}
__device__ __forceinline__ float lrelu(float x){ return x > 0.f ? x : 0.01f * x; }

// ---------------------------------------------------------------------------
// Stage 1: BN statistics (sum, sumsq) per (agent, feature).
// ---------------------------------------------------------------------------
__global__ __launch_bounds__(256) void k_stats(
    const float* __restrict__ states, const float* __restrict__ actions,
    float* __restrict__ part)
{
  int a = blockIdx.y;
  int chunk = blockIdx.x;
  int t = threadIdx.x;
  int r0 = chunk * (B_N / CHUNKS);   // 256 rows per chunk
  __shared__ float red[512];
  {
    int f = t & 127, half = t >> 7;
    const float* p = states + ((size_t)a * B_N + r0 + half) * IN_N + f;
    float s1 = 0.f, s2 = 0.f;
    for (int it = 0; it < 128; ++it){
      float v = p[(size_t)(2 * it) * IN_N];
      s1 += v; s2 += v * v;
    }
    red[t] = s1; red[256 + t] = s2;
    __syncthreads();
    if (t < 128){
      float a1 = red[t] + red[t + 128];
      float a2 = red[256 + t] + red[256 + t + 128];
      size_t o = (((size_t)a * CHUNKS + chunk) * SAF + t) * 2;
      part[o] = a1; part[o + 1] = a2;
    }
    __syncthreads();
  }
  {
    int f = t & 31, g = t >> 5;
    const float* p = actions + ((size_t)a * B_N + r0 + g) * OUT_N + f;
    float s1 = 0.f, s2 = 0.f;
    for (int it = 0; it < 32; ++it){
      float v = p[(size_t)(8 * it) * OUT_N];
      s1 += v; s2 += v * v;
    }
    red[t] = s1; red[256 + t] = s2;
    __syncthreads();
    if (t < 32){
      float a1 = 0.f, a2 = 0.f;
      #pragma unroll
      for (int gg = 0; gg < 8; ++gg){
        a1 += red[t + 32 * gg];
        a2 += red[256 + t + 32 * gg];
      }
      size_t o = (((size_t)a * CHUNKS + chunk) * SAF + 128 + t) * 2;
      part[o] = a1; part[o + 1] = a2;
    }
  }
}

__global__ void k_finalize(const float* __restrict__ part,
                           float* __restrict__ meanArr, float* __restrict__ istdArr)
{
  int idx = blockIdx.x * blockDim.x + threadIdx.x;
  if (idx >= A_N * SAF) return;
  int a = idx / SAF, f = idx % SAF;
  float s1 = 0.f, s2 = 0.f;
  for (int c = 0; c < CHUNKS; ++c){
    size_t o = (((size_t)a * CHUNKS + c) * SAF + f) * 2;
    s1 += part[o]; s2 += part[o + 1];
  }
  float m = s1 * (1.f / B_N);
  float v = s2 * (1.f / B_N) - m * m;
  if (v < 0.f) v = 0.f;
  meanArr[idx] = m;
  istdArr[idx] = rsqrtf(v + EPSV);
}

// ---------------------------------------------------------------------------
// Weight pre-pack, TILE-MAJOR for global_load_lds:
//   layout = [k-tile][128 n][32 k] contiguous (4096 u16 = 8192 B per tile),
//   with the 16B-unit swizzle BAKED IN (dst = prefix | swzi(rr)).
// enc/c1: hi/lo bf16 pairs; key/sel/val: single bf16.
// ---------------------------------------------------------------------------
__device__ __forceinline__ void packpair(float w, u16* __restrict__ dh,
                                         u16* __restrict__ dl, int i){
  u16 h = f2bf(w);
  dh[i] = h;
  dl[i] = f2bf(w - bf2f(h));
}

__global__ __launch_bounds__(256) void k_pack(
    const float* __restrict__ enc_w, const float* __restrict__ aenc_w,
    const float* __restrict__ key_w, const float* __restrict__ sel_w,
    const float* __restrict__ val_w, const float* __restrict__ c1_w,
    u16* __restrict__ encH, u16* __restrict__ encL,
    u16* __restrict__ aencH, u16* __restrict__ aencL,
    u16* __restrict__ keyH, u16* __restrict__ selH, u16* __restrict__ valH,
    u16* __restrict__ c1H, u16* __restrict__ c1L)
{
  int i = blockIdx.x * 256 + threadIdx.x;
  const int S0 = A_N * H_N * SAF;      // 163840 enc (5 tiles/agent)
  const int S1 = A_N * H_N * OUT_N;    // 32768 aenc
  const int S2 = KD_N * H_N;           // 16384 per key/sel/val (4 tiles)
  const int S5 = A_N * H_N * CIN_N;    // 262144 c1 (8 tiles/agent)
  if (i < S0){
    int a = i / (H_N * SAF); int r = i % (H_N * SAF);
    int tile = r >> 12; int rr = r & 4095;
    int n = rr >> 5; int kk = rr & 31;
    int kg = tile * 32 + kk;
    int d = (i & ~4095) | swzi(rr);
    packpair(enc_w[((size_t)a * SAF + kg) * H_N + n], encH, encL, d);
    return;
  }
  i -= S0;
  if (i < S1){
    int a = i >> 12; int rr = i & 4095;
    int n = rr >> 5; int k = rr & 31;
    int d = (i & ~4095) | swzi(rr);
    packpair(aenc_w[((size_t)a * OUT_N + k) * H_N + n], aencH, aencL, d);
    return;
  }
  i -= S1;
  if (i < 3 * S2){
    int which = i / S2; int j = i % S2;
    int tile = j >> 12; int rr = j & 4095;
    int n = rr >> 5; int kk = rr & 31;
    int kg = tile * 32 + kk;
    const float* w = (which == 0) ? key_w : ((which == 1) ? sel_w : val_w);
    u16* dh = (which == 0) ? keyH : ((which == 1) ? selH : valH);
    dh[(j & ~4095) | swzi(rr)] =
        f2bf(w[(((size_t)(n >> 5)) * H_N + kg) * D_N + (n & 31)]);
    return;
  }
  i -= 3 * S2;
  if (i < S5){
    int a = i >> 15; int r = i & 32767;
    int tile = r >> 12; int rr = r & 4095;
    int n = rr >> 5; int kk = rr & 31;
    int kg = tile * 32 + kk;
    int d = (i & ~4095) | swzi(rr);
    packpair(c1_w[((size_t)a * CIN_N + kg) * H_N + n], c1H, c1L, d);
  }
}
#define PACK_TOTAL (A_N*H_N*SAF + A_N*H_N*OUT_N + 3*KD_N*H_N + A_N*H_N*CIN_N)

// ---------------------------------------------------------------------------
// Fused kernel 1: sa_enc = lrelu(BN(concat) @ enc_w + enc_b)  [3-term, BK=32,
//   K=160], sels = sa_enc @ sel_w [1-term, BK=64].
// Synchronous structure; weight tiles linear-glds from swizzle-baked pack,
// frag reads XOR-compensated.
// ---------------------------------------------------------------------------
__global__ __launch_bounds__(256, 3) void k_enc_sel(
    const float* __restrict__ states, const float* __restrict__ actions,
    const float* __restrict__ mean, const float* __restrict__ istd,
    const u16* __restrict__ encH, const u16* __restrict__ encL,
    const float* __restrict__ enc_b,
    const u16* __restrict__ selH,
    u16* __restrict__ sa_enc, u16* __restrict__ sels)
{
  int a = blockIdx.y; int row0 = blockIdx.x * 128; int t = threadIdx.x;
  int lane = t & 63, wave = t >> 6, l16 = lane & 15, quad = lane >> 4;
  __shared__ __align__(16) u16 S[25600];
  __shared__ __align__(16) float sc[160], sh[160];
  u16* Wh = S;            // [128][32] enc weight hi tile (phase 1)
  u16* Wl = S + 4096;     // [128][32]
  u16* Xh = S + 8192;     // [128][40]
  u16* Xl = S + 13312;    // [128][40]
  u16* T  = S;            // [128][136] (phase-1 output / phase-2 A)
  u16* Ws = S + 17408;    // [2][128][32] sel weight tiles (phase 2)

  if (t < SAF){
    float m = mean[a * SAF + t], s = istd[a * SAF + t];
    sc[t] = s; sh[t] = -m * s;
  }
  floatx4 acc[2][8];
  #pragma unroll
  for (int mt = 0; mt < 2; ++mt)
    #pragma unroll
    for (int nt = 0; nt < 8; ++nt) acc[mt][nt] = (floatx4){0.f,0.f,0.f,0.f};
  const u16* ebh = encH + (size_t)a * (H_N * SAF);
  const u16* ebl = encL + (size_t)a * (H_N * SAF);
  __syncthreads();

  // ---- phase 1: enc GEMM (3-term split), K=160, BK=32 ----
  for (int k0 = 0; k0 < SAF; k0 += 32){
    const u16* th = ebh + (k0 >> 5) * 4096;
    const u16* tl = ebl + (k0 >> 5) * 4096;
    #pragma unroll
    for (int c = t; c < 512; c += 256){
      glds16(th + c * 8, Wh + c * 8);
      glds16(tl + c * 8, Wl + c * 8);
    }
    for (int c = t; c < 1024; c += 256){
      int r = c >> 3, kc = (c & 7) * 4, f = k0 + kc;
      size_t row = (size_t)a * B_N + row0 + r;
      float4 v;
      if (f < IN_N) v = *(const float4*)(states + row * IN_N + f);
      else          v = *(const float4*)(actions + row * OUT_N + (f - IN_N));
      float4 scv = *(const float4*)&sc[f];
      float4 shv = *(const float4*)&sh[f];
      float x0 = fmaf(v.x, scv.x, shv.x), x1 = fmaf(v.y, scv.y, shv.y);
      float x2 = fmaf(v.z, scv.z, shv.z), x3 = fmaf(v.w, scv.w, shv.w);
      u16 h0 = f2bf(x0), h1 = f2bf(x1), h2 = f2bf(x2), h3 = f2bf(x3);
      uint2 hv; hv.x = (u32)h0 | ((u32)h1 << 16); hv.y = (u32)h2 | ((u32)h3 << 16);
      *(uint2*)&Xh[r * 40 + kc] = hv;
      u16 l0 = f2bf(x0 - bf2f(h0)), l1 = f2bf(x1 - bf2f(h1));
      u16 l2 = f2bf(x2 - bf2f(h2)), l3 = f2bf(x3 - bf2f(h3));
      uint2 lv; lv.x = (u32)l0 | ((u32)l1 << 16); lv.y = (u32)l2 | ((u32)l3 << 16);
      *(uint2*)&Xl[r * 40 + kc] = lv;
    }
    __syncthreads();
    {
      short8 ah[2], al[2], bh[8], bl[8];
      #pragma unroll
      for (int mt = 0; mt < 2; ++mt){
        int rr = (wave * 32 + mt * 16 + l16) * 40 + quad * 8;
        ah[mt] = *(const short8*)&Xh[rr];
        al[mt] = *(const short8*)&Xl[rr];
      }
      #pragma unroll
      for (int nt = 0; nt < 8; ++nt){
        int v = (nt * 16 + l16) * 4 + quad; v ^= (v >> 3) & 3;
        bh[nt] = *(const short8*)&Wh[v * 8];
        bl[nt] = *(const short8*)&Wl[v * 8];
      }
      #pragma unroll
      for (int mt = 0; mt < 2; ++mt)
        #pragma unroll
        for (int nt = 0; nt < 8; ++nt){
          acc[mt][nt] = __builtin_amdgcn_mfma_f32_16x16x32_bf16(ah[mt], bh[nt], acc[mt][nt], 0,0,0);
          acc[mt][nt] = __builtin_amdgcn_mfma_f32_16x16x32_bf16(ah[mt], bl[nt], acc[mt][nt], 0,0,0);
          acc[mt][nt] = __builtin_amdgcn_mfma_f32_16x16x32_bf16(al[mt], bh[nt], acc[mt][nt], 0,0,0);
        }
    }
    __syncthreads();
  }

  // ---- phase-1 epilogue: lrelu+bias -> bf16 tile T in LDS ----
  {
    float bv[8];
    #pragma unroll
    for (int nt = 0; nt < 8; ++nt) bv[nt] = enc_b[a * H_N + nt * 16 + l16];
    #pragma unroll
    for (int mt = 0; mt < 2; ++mt)
      #pragma unroll
      for (int nt = 0; nt < 8; ++nt)
        #pragma unroll
        for (int r = 0; r < 4; ++r){
          int rl = wave * 32 + mt * 16 + quad * 4 + r;
          T[rl * 136 + nt * 16 + l16] = f2bf(lrelu(acc[mt][nt][r] + bv[nt]));
        }
  }
  __syncthreads();
  // vectorized sa_enc store from tile
  for (int c = t; c < 2048; c += 256){
    int row = c >> 4, col8 = (c & 15) * 8;
    *(uint4*)(sa_enc + ((size_t)a * B_N + row0 + row) * H_N + col8) =
        *(const uint4*)&T[row * 136 + col8];
  }

  // ---- phase 2: sels = T @ selT (single-term), BK=64 ----
  #pragma unroll
  for (int mt = 0; mt < 2; ++mt)
    #pragma unroll
    for (int nt = 0; nt < 8; ++nt) acc[mt][nt] = (floatx4){0.f,0.f,0.f,0.f};
  for (int k0 = 0; k0 < H_N; k0 += 64){
    #pragma unroll
    for (int c = t; c < 1024; c += 256)
      glds16(selH + (k0 >> 5) * 4096 + c * 8, Ws + c * 8);
    __syncthreads();
    #pragma unroll
    for (int ks = 0; ks < 64; ks += 32){
      short8 ah[2], bh[8];
      #pragma unroll
      for (int mt = 0; mt < 2; ++mt)
        ah[mt] = *(const short8*)&T[(wave * 32 + mt * 16 + l16) * 136 + k0 + ks + quad * 8];
      #pragma unroll
      for (int nt = 0; nt < 8; ++nt){
        int v = ((ks >> 5) << 9) + (nt * 16 + l16) * 4 + quad; v ^= (v >> 3) & 3;
        bh[nt] = *(const short8*)&Ws[v * 8];
      }
      #pragma unroll
      for (int mt = 0; mt < 2; ++mt)
        #pragma unroll
        for (int nt = 0; nt < 8; ++nt)
          acc[mt][nt] = __builtin_amdgcn_mfma_f32_16x16x32_bf16(ah[mt], bh[nt], acc[mt][nt], 0,0,0);
    }
    __syncthreads();
  }
  #pragma unroll
  for (int mt = 0; mt < 2; ++mt)
    #pragma unroll
    for (int nt = 0; nt < 8; ++nt)
      #pragma unroll
      for (int r = 0; r < 4; ++r){
        int rl = wave * 32 + mt * 16 + quad * 4 + r;
        T[rl * 136 + nt * 16 + l16] = f2bf(acc[mt][nt][r]);
      }
  __syncthreads();
  for (int c = t; c < 2048; c += 256){
    int row = c >> 4, col8 = (c & 15) * 8;
    *(uint4*)(sels + ((size_t)a * B_N + row0 + row) * H_N + col8) =
        *(const uint4*)&T[row * 136 + col8];
  }
}

// ---------------------------------------------------------------------------
// Fused kernel 2: a_enc = lrelu(BN(actions) @ aenc_w + aenc_b) [3-term, K=32]
//   keys & vals in ONE dual-accumulator loop (weights linear-glds from
//   swizzle-baked pack).
// ---------------------------------------------------------------------------
__global__ __launch_bounds__(256, 2) void k_aenc_kv(
    const float* __restrict__ actions,
    const float* __restrict__ mean, const float* __restrict__ istd,
    const u16* __restrict__ aencH, const u16* __restrict__ aencL,
    const float* __restrict__ aenc_b,
    const u16* __restrict__ keyH, const u16* __restrict__ valH,
    const float* __restrict__ val_b,
    u16* __restrict__ keys, u16* __restrict__ vals)
{
  int a = blockIdx.y; int row0 = blockIdx.x * 128; int t = threadIdx.x;
  int lane = t & 63, wave = t >> 6, l16 = lane & 15, quad = lane >> 4;
  __shared__ __align__(16) u16 S[34816];
  __shared__ __align__(16) float sc[32], sh[32];
  u16* T  = S;            // [128][136] a_enc tile; later vals tile
  u16* WK = S + 17408;    // [2][128][32] key weight tiles
  u16* WV = S + 25600;    // [2][128][32] val weight tiles
  u16* T2 = S + 17408;    // [128][136] keys tile (epilogue)

  if (t < 32){
    float m = mean[a * SAF + 128 + t], s = istd[a * SAF + 128 + t];
    sc[t] = s; sh[t] = -m * s;
  }
  floatx4 accK[2][8], accV[2][8];
  #pragma unroll
  for (int mt = 0; mt < 2; ++mt)
    #pragma unroll
    for (int nt = 0; nt < 8; ++nt){
      accK[mt][nt] = (floatx4){0.f,0.f,0.f,0.f};
      accV[mt][nt] = (floatx4){0.f,0.f,0.f,0.f};
    }
  __syncthreads();

  // ---- phase 1: aenc GEMM, K=32 single tile ----
  {
    u16* Wh1 = S;  u16* Wl1 = S + 4096;
    u16* Xh = S + 8192; u16* Xl = S + 13312;  // [128][40]
    const u16* abh = aencH + (size_t)a * 4096;
    const u16* abl = aencL + (size_t)a * 4096;
    #pragma unroll
    for (int c = t; c < 512; c += 256){
      glds16(abh + c * 8, Wh1 + c * 8);
      glds16(abl + c * 8, Wl1 + c * 8);
    }
    for (int c = t; c < 1024; c += 256){
      int r = c >> 3, kc = (c & 7) * 4;
      size_t row = (size_t)a * B_N + row0 + r;
      float4 v = *(const float4*)(actions + row * OUT_N + kc);
      float4 scv = *(const float4*)&sc[kc];
      float4 shv = *(const float4*)&sh[kc];
      float x0 = fmaf(v.x, scv.x, shv.x), x1 = fmaf(v.y, scv.y, shv.y);
      float x2 = fmaf(v.z, scv.z, shv.z), x3 = fmaf(v.w, scv.w, shv.w);
      u16 h0 = f2bf(x0), h1 = f2bf(x1), h2 = f2bf(x2), h3 = f2bf(x3);
      uint2 hv; hv.x = (u32)h0 | ((u32)h1 << 16); hv.y = (u32)h2 | ((u32)h3 << 16);
      *(uint2*)&Xh[r * 40 + kc] = hv;
      u16 l0 = f2bf(x0 - bf2f(h0)), l1 = f2bf(x1 - bf2f(h1));
      u16 l2 = f2bf(x2 - bf2f(h2)), l3 = f2bf(x3 - bf2f(h3));
      uint2 lv; lv.x = (u32)l0 | ((u32)l1 << 16); lv.y = (u32)l2 | ((u32)l3 << 16);
      *(uint2*)&Xl[r * 40 + kc] = lv;
    }
    __syncthreads();
    short8 ah[2], al[2], bh[8], bl[8];
    #pragma unroll
    for (int mt = 0; mt < 2; ++mt){
      int rr = (wave * 32 + mt * 16 + l16) * 40 + quad * 8;
      ah[mt] = *(const short8*)&Xh[rr];
      al[mt] = *(const short8*)&Xl[rr];
    }
    #pragma unroll
    for (int nt = 0; nt < 8; ++nt){
      int v = (nt * 16 + l16) * 4 + quad; v ^= (v >> 3) & 3;
      bh[nt] = *(const short8*)&Wh1[v * 8];
      bl[nt] = *(const short8*)&Wl1[v * 8];
    }
    #pragma unroll
    for (int mt = 0; mt < 2; ++mt)
      #pragma unroll
      for (int nt = 0; nt < 8; ++nt){
        accK[mt][nt] = __builtin_amdgcn_mfma_f32_16x16x32_bf16(ah[mt], bh[nt], accK[mt][nt], 0,0,0);
        accK[mt][nt] = __builtin_amdgcn_mfma_f32_16x16x32_bf16(ah[mt], bl[nt], accK[mt][nt], 0,0,0);
        accK[mt][nt] = __builtin_amdgcn_mfma_f32_16x16x32_bf16(al[mt], bh[nt], accK[mt][nt], 0,0,0);
      }
    __syncthreads();
  }
  // a_enc -> LDS tile T; move from accK, then zero accK
  {
    float bv[8];
    #pragma unroll
    for (int nt = 0; nt < 8; ++nt) bv[nt] = aenc_b[a * H_N + nt * 16 + l16];
    #pragma unroll
    for (int mt = 0; mt < 2; ++mt)
      #pragma unroll
      for (int nt = 0; nt < 8; ++nt){
        #pragma unroll
        for (int r = 0; r < 4; ++r){
          int rl = wave * 32 + mt * 16 + quad * 4 + r;
          T[rl * 136 + nt * 16 + l16] = f2bf(lrelu(accK[mt][nt][r] + bv[nt]));
        }
        accK[mt][nt] = (floatx4){0.f,0.f,0.f,0.f};
      }
  }

  // ---- phase 2: keys + vals in one dual-acc loop (BK=64, single-term) ----
  for (int k0 = 0; k0 < H_N; k0 += 64){
    __syncthreads();
    #pragma unroll
    for (int c = t; c < 1024; c += 256){
      glds16(keyH + (k0 >> 5) * 4096 + c * 8, WK + c * 8);
      glds16(valH + (k0 >> 5) * 4096 + c * 8, WV + c * 8);
    }
    __syncthreads();
    #pragma unroll
    for (int ks = 0; ks < 64; ks += 32){
      short8 ah[2], bk[8], bv[8];
      #pragma unroll
      for (int mt = 0; mt < 2; ++mt)
        ah[mt] = *(const short8*)&T[(wave * 32 + mt * 16 + l16) * 136 + k0 + ks + quad * 8];
      #pragma unroll
      for (int nt = 0; nt < 8; ++nt){
        int v = ((ks >> 5) << 9) + (nt * 16 + l16) * 4 + quad; v ^= (v >> 3) & 3;
        bk[nt] = *(const short8*)&WK[v * 8];
        bv[nt] = *(const short8*)&WV[v * 8];
      }
      #pragma unroll
      for (int mt = 0; mt < 2; ++mt)
        #pragma unroll
        for (int nt = 0; nt < 8; ++nt){
          accK[mt][nt] = __builtin_amdgcn_mfma_f32_16x16x32_bf16(ah[mt], bk[nt], accK[mt][nt], 0,0,0);
          accV[mt][nt] = __builtin_amdgcn_mfma_f32_16x16x32_bf16(ah[mt], bv[nt], accV[mt][nt], 0,0,0);
        }
    }
  }
  __syncthreads();
  // epilogue: vals -> T (with bias+lrelu), keys -> T2; both vectorized
  {
    float bv[8];
    #pragma unroll
    for (int nt = 0; nt < 8; ++nt) bv[nt] = val_b[nt * 16 + l16];
    #pragma unroll
    for (int mt = 0; mt < 2; ++mt)
      #pragma unroll
      for (int nt = 0; nt < 8; ++nt)
        #pragma unroll
        for (int r = 0; r < 4; ++r){
          int rl = wave * 32 + mt * 16 + quad * 4 + r;
          T[rl * 136 + nt * 16 + l16]  = f2bf(lrelu(accV[mt][nt][r] + bv[nt]));
          T2[rl * 136 + nt * 16 + l16] = f2bf(accK[mt][nt][r]);
        }
  }
  __syncthreads();
  for (int c = t; c < 2048; c += 256){
    int row = c >> 4, col8 = (c & 15) * 8;
    *(uint4*)(vals + ((size_t)a * B_N + row0 + row) * H_N + col8) =
        *(const uint4*)&T[row * 136 + col8];
    *(uint4*)(keys + ((size_t)a * B_N + row0 + row) * H_N + col8) =
        *(const uint4*)&T2[row * 136 + col8];
  }
}

// ---------------------------------------------------------------------------
// Attention. LDS tiles permuted at 16B-unit granularity:
//   U(aa,bl,kk,dg) = (bl*4+dg)*32 + kk*8 + (aa ^ (kk<<1) ^ dg)
// Old row-major layout made the si gather a 32-way bank conflict. Permuted:
// staging writes and K/V dot reads 2-way (free). Same 24 KB. `other` may
// alias `keys` (reads complete before __syncthreads; rows disjoint).
// ---------------------------------------------------------------------------
__global__ __launch_bounds__(256) void k_attn(
    const u16* __restrict__ sels, const u16* __restrict__ keys,
    const u16* __restrict__ vals, u16* __restrict__ other)
{
  int b0 = blockIdx.x * 8;
  int t = threadIdx.x;
  __shared__ __align__(16) u16 sS[8192], sK[8192], sV[8192];
  #pragma unroll
  for (int c = t; c < 1024; c += 256){
    int pr = c >> 4, uir = c & 15;
    int aa = pr & 7, bl2 = pr >> 3;
    int kk = uir >> 2, dg = uir & 3;
    int U = (bl2 * 4 + dg) * 32 + kk * 8 + (aa ^ (kk << 1) ^ dg);
    size_t go = ((size_t)aa * B_N + b0 + bl2) * KD_N;
    ((uint4*)sS)[U] = *((const uint4*)(sels + go) + uir);
    ((uint4*)sK)[U] = *((const uint4*)(keys + go) + uir);
    ((uint4*)sV)[U] = *((const uint4*)(vals + go) + uir);
  }
  __syncthreads();
  int i = t & 7, k = (t >> 3) & 3, bl = t >> 5;
  float si[32];
  #pragma unroll
  for (int dg = 0; dg < 4; ++dg){
    int U = (bl * 4 + dg) * 32 + k * 8 + (i ^ (k << 1) ^ dg);
    uint4 s4 = ((const uint4*)sS)[U];
    const u32* sp = (const u32*)&s4;
    #pragma unroll
    for (int jj = 0; jj < 4; ++jj){
      int d2 = dg * 4 + jj;
      si[2 * d2] = bf_lo(sp[jj]); si[2 * d2 + 1] = bf_hi(sp[jj]);
    }
  }
  float lg[8];
  #pragma unroll
  for (int j = 0; j < 8; ++j){
    float acc = 0.f;
    #pragma unroll
    for (int dg = 0; dg < 4; ++dg){
      int U = (bl * 4 + dg) * 32 + k * 8 + (j ^ (k << 1) ^ dg);
      uint4 k4 = ((const uint4*)sK)[U];
      const u32* kp = (const u32*)&k4;
      #pragma unroll
      for (int jj = 0; jj < 4; ++jj){
        int d2 = dg * 4 + jj;
        acc = fmaf(si[2 * d2], bf_lo(kp[jj]), acc);
        acc = fmaf(si[2 * d2 + 1], bf_hi(kp[jj]), acc);
      }
    }
    lg[j] = acc * 0.17677669529663689f;
  }
  float mx = -3.0e38f;
  #pragma unroll
  for (int j = 0; j < 8; ++j) if (j != i) mx = fmaxf(mx, lg[j]);
  float pe[8], se = 0.f;
  #pragma unroll
  for (int j = 0; j < 8; ++j){
    pe[j] = (j == i) ? 0.f : __expf(lg[j] - mx);
    se += pe[j];
  }
  float inv = 1.f / se;
  #pragma unroll
  for (int j = 0; j < 8; ++j) pe[j] *= inv;
  float o0[16], o1[16];
  #pragma unroll
  for (int d2 = 0; d2 < 16; ++d2){ o0[d2] = 0.f; o1[d2] = 0.f; }
  #pragma unroll
  for (int j = 0; j < 8; ++j){
    #pragma unroll
    for (int dg = 0; dg < 4; ++dg){
      int U = (bl * 4 + dg) * 32 + k * 8 + (j ^ (k << 1) ^ dg);
      uint4 v4 = ((const uint4*)sV)[U];
      const u32* vp = (const u32*)&v4;
      #pragma unroll
      for (int jj = 0; jj < 4; ++jj){
        int d2 = dg * 4 + jj;
        o0[d2] = fmaf(pe[j], bf_lo(vp[jj]), o0[d2]);
        o1[d2] = fmaf(pe[j], bf_hi(vp[jj]), o1[d2]);
      }
    }
  }
  __align__(16) u16 ob[32];
  #pragma unroll
  for (int d2 = 0; d2 < 16; ++d2){
    ob[2 * d2] = f2bf(o0[d2]); ob[2 * d2 + 1] = f2bf(o1[d2]);
  }
  uint4* dst = (uint4*)(other + ((size_t)i * B_N + (b0 + bl)) * KD_N + k * 32);
  const uint4* s4o = (const uint4*)ob;
  #pragma unroll
  for (int c = 0; c < 4; ++c) dst[c] = s4o[c];
}

// ---------------------------------------------------------------------------
// Critic: h = lrelu([sa_enc|other] @ c1_w + c1_b); q = h . c2_w + c2_b
// Synchronous single-buffer; W tiles linear-glds from swizzle-baked pack
// (XOR reads); X tile linear glds + linear reads (producer layout untouched).
// LDS 24576 B.
// ---------------------------------------------------------------------------
__global__ __launch_bounds__(256, 3) void k_critic(
    const u16* __restrict__ sa_enc, const u16* __restrict__ other,
    const u16* __restrict__ c1H, const u16* __restrict__ c1L,
    const float* __restrict__ c1_b,
    const float* __restrict__ c2w, const float* __restrict__ c2b,
    float* __restrict__ qout)
{
  int a = blockIdx.y; int row0 = blockIdx.x * 128; int t = threadIdx.x;
  int lane = t & 63, wave = t >> 6, l16 = lane & 15, quad = lane >> 4;
  __shared__ __align__(16) u16 Xs[4096];
  __shared__ __align__(16) u16 Wh[4096];
  __shared__ __align__(16) u16 Wl[4096];
  floatx4 acc[2][8];
  #pragma unroll
  for (int mt = 0; mt < 2; ++mt)
    #pragma unroll
    for (int nt = 0; nt < 8; ++nt) acc[mt][nt] = (floatx4){0.f,0.f,0.f,0.f};
  const u16* wbh = c1H + (size_t)a * (H_N * CIN_N);
  const u16* wbl = c1L + (size_t)a * (H_N * CIN_N);

  for (int kt = 0; kt < 8; ++kt){
    const u16* th = wbh + kt * 4096;
    const u16* tl = wbl + kt * 4096;
    #pragma unroll
    for (int c = t; c < 512; c += 256){
      glds16(th + c * 8, Wh + c * 8);
      glds16(tl + c * 8, Wl + c * 8);
    }
    {
      const u16* src = (kt < 4) ? sa_enc : other;
      int kb = (kt < 4) ? kt * 32 : kt * 32 - H_N;
      #pragma unroll
      for (int c = t; c < 512; c += 256){
        int r = c >> 2, off = (c & 3) * 8;
        glds16(src + ((size_t)a * B_N + row0 + r) * H_N + kb + off, Xs + c * 8);
      }
    }
    __syncthreads();
    {
      short8 ah[2], bh[8], bl[8];
      #pragma unroll
      for (int mt = 0; mt < 2; ++mt)
        ah[mt] = *(const short8*)&Xs[(wave * 32 + mt * 16 + l16) * 32 + quad * 8];
      #pragma unroll
      for (int nt = 0; nt < 8; ++nt){
        int v = (nt * 16 + l16) * 4 + quad; v ^= (v >> 3) & 3;
        bh[nt] = *(const short8*)&Wh[v * 8];
        bl[nt] = *(const short8*)&Wl[v * 8];
      }
      #pragma unroll
      for (int mt = 0; mt < 2; ++mt)
        #pragma unroll
        for (int nt = 0; nt < 8; ++nt){
          acc[mt][nt] = __builtin_amdgcn_mfma_f32_16x16x32_bf16(ah[mt], bh[nt], acc[mt][nt], 0,0,0);
          acc[mt][nt] = __builtin_amdgcn_mfma_f32_16x16x32_bf16(ah[mt], bl[nt], acc[mt][nt], 0,0,0);
        }
    }
    __syncthreads();
  }

  float c2r[8], bv[8];
  #pragma unroll
  for (int nt = 0; nt < 8; ++nt){
    c2r[nt] = c2w[a * H_N + nt * 16 + l16];
    bv[nt]  = c1_b[a * H_N + nt * 16 + l16];
  }
  #pragma unroll
  for (int mt = 0; mt < 2; ++mt){
    #pragma unroll
    for (int r = 0; r < 4; ++r){
      float s = 0.f;
      #pragma unroll
      for (int nt = 0; nt < 8; ++nt){
        float h = lrelu(acc[mt][nt][r] + bv[nt]);
        s = fmaf(h, c2r[nt], s);
      }
      s += __shfl_xor(s, 1);
      s += __shfl_xor(s, 2);
      s += __shfl_xor(s, 4);
      s += __shfl_xor(s, 8);
      if (l16 == 0){
        int row = row0 + wave * 32 + mt * 16 + quad * 4 + r;
        qout[(size_t)a * B_N + row] = s + c2b[a];
      }
    }
  }
}

// ---------------------------------------------------------------------------
extern "C" void kernel_launch(void* const* d_in, const int* in_sizes, int n_in,
                              void* d_out, int out_size, void* d_ws, size_t ws_size,
                              hipStream_t stream)
{
  const float* states  = (const float*)d_in[0];
  const float* actions = (const float*)d_in[1];
  const float* enc_w   = (const float*)d_in[2];
  const float* enc_b   = (const float*)d_in[3];
  const float* aenc_w  = (const float*)d_in[4];
  const float* aenc_b  = (const float*)d_in[5];
  const float* key_w   = (const float*)d_in[6];
  const float* sel_w   = (const float*)d_in[7];
  const float* val_w   = (const float*)d_in[8];
  const float* val_b   = (const float*)d_in[9];
  const float* c1_w    = (const float*)d_in[10];
  const float* c1_b    = (const float*)d_in[11];
  const float* c2_w    = (const float*)d_in[12];
  const float* c2_b    = (const float*)d_in[13];
  float* q = (float*)d_out;

  char* ws = (char*)d_ws;
  // Pack region [0, 884,736) overlaps stats partials [0, 1,310,720):
  // stats/finalize consume `part` before k_pack overwrites (sequential stream).
  u16* encH  = (u16*)(ws + 0);          // 327680 B
  u16* encL  = (u16*)(ws + 327680);     // 327680 B
  u16* aencH = (u16*)(ws + 655360);     //  65536 B
  u16* aencL = (u16*)(ws + 720896);     //  65536 B
  u16* keyH  = (u16*)(ws + 786432);     //  32768 B
  u16* selH  = (u16*)(ws + 819200);     //  32768 B
  u16* valH  = (u16*)(ws + 851968);     //  32768 B -> ends 884,736
  float* part    = (float*)ws;          // 1,310,720 B (dead after finalize)
  float* meanArr = (float*)(ws + 1310720);
  float* istdArr = (float*)(ws + 1315840);
  u16* c1H = (u16*)(ws + 1320960);      // 524288 B
  u16* c1L = (u16*)(ws + 1845248);      // 524288 B -> ends 2,369,536
  const size_t ibase = 4194304;
  const size_t BUF = (size_t)A_N * B_N * 128 * 2;   // 64 MB
  u16* sa_enc = (u16*)(ws + ibase);
  u16* sels   = (u16*)(ws + ibase + BUF);
  u16* keys   = (u16*)(ws + ibase + 2 * BUF);       // keys, later `other`
  u16* vals   = (u16*)(ws + ibase + 3 * BUF);

  k_stats<<<dim3(CHUNKS, A_N), 256, 0, stream>>>(states, actions, part);
  k_finalize<<<(A_N * SAF + 255) / 256, 256, 0, stream>>>(part, meanArr, istdArr);
  k_pack<<<(PACK_TOTAL + 255) / 256, 256, 0, stream>>>(
      enc_w, aenc_w, key_w, sel_w, val_w, c1_w,
      encH, encL, aencH, aencL, keyH, selH, valH, c1H, c1L);

  dim3 g(B_N / 128, A_N);
  k_enc_sel<<<g, 256, 0, stream>>>(states, actions, meanArr, istdArr,
                                   encH, encL, enc_b, selH, sa_enc, sels);
  k_aenc_kv<<<g, 256, 0, stream>>>(actions, meanArr, istdArr,
                                   aencH, aencL, aenc_b, keyH, valH, val_b,
                                   keys, vals);
  k_attn<<<B_N / 8, 256, 0, stream>>>(sels, keys, vals, keys);  // other -> keys
  k_critic<<<g, 256, 0, stream>>>(sa_enc, keys, c1H, c1L, c1_b, c2_w, c2_b, q);
}